// Round 2
// baseline (2067.567 us; speedup 1.0000x reference)
//
#include <hip/hip_runtime.h>
#include <math.h>

#define N_NODES 100000
#define N_EDGES 1600000
#define NCLS_ 40

// ---------------------------------------------------------------- utils
__global__ void zero_i32_kernel(int* __restrict__ p, int n) {
    int i = blockIdx.x * blockDim.x + threadIdx.x;
    if (i < n) p[i] = 0;
}
__global__ void zero_f32_kernel(float* __restrict__ p, int n) {
    int i = blockIdx.x * blockDim.x + threadIdx.x;
    if (i < n) p[i] = 0.0f;
}

// ---------------------------------------------------------------- CSR build
__global__ void hist_kernel(const int* __restrict__ dst, int* __restrict__ deg) {
    int i = blockIdx.x * blockDim.x + threadIdx.x;
    int stride = gridDim.x * blockDim.x;
    for (; i < N_EDGES; i += stride) atomicAdd(&deg[dst[i]], 1);
}

__global__ void scan_kernel(const int* __restrict__ deg, int* __restrict__ rowptr) {
    __shared__ int tmp[1024];
    __shared__ int s_off;
    int t = threadIdx.x;
    if (t == 0) s_off = 0;
    __syncthreads();
    for (int base = 0; base < N_NODES; base += 1024) {
        int i = base + t;
        int v = (i < N_NODES) ? deg[i] : 0;
        tmp[t] = v;
        __syncthreads();
        for (int d = 1; d < 1024; d <<= 1) {
            int add = (t >= d) ? tmp[t - d] : 0;
            __syncthreads();
            tmp[t] += add;
            __syncthreads();
        }
        int off = s_off;
        if (i < N_NODES) rowptr[i] = off + tmp[t] - v;   // exclusive
        __syncthreads();
        if (t == 0) s_off = off + tmp[1023];
        __syncthreads();
    }
    if (t == 0) rowptr[N_NODES] = s_off;
}

__global__ void copy_kernel(const int* __restrict__ a, int* __restrict__ b) {
    int i = blockIdx.x * blockDim.x + threadIdx.x;
    int stride = gridDim.x * blockDim.x;
    for (; i < N_NODES; i += stride) b[i] = a[i];
}

__global__ void scatter_kernel(const int* __restrict__ dst, int* __restrict__ cursor,
                               int* __restrict__ eids) {
    int i = blockIdx.x * blockDim.x + threadIdx.x;
    int stride = gridDim.x * blockDim.x;
    for (; i < N_EDGES; i += stride) {
        int pos = atomicAdd(&cursor[dst[i]], 1);
        eids[pos] = i;
    }
}

// ---------------------------------------------------------------- paired GEMM
// out[N,256] = A[N,128] @ [W0|W1] + [b0|b1].  64x64 tile, 4x4 micro, fp32 VALU.
__global__ __launch_bounds__(256) void gemm_pair_kernel(
    const float* __restrict__ A,
    const float* __restrict__ W0, const float* __restrict__ W1,
    const float* __restrict__ b0, const float* __restrict__ b1,
    float* __restrict__ out) {
    __shared__ float As[64][132];   // pad 132: As[r][k] broadcast rows spread banks
    __shared__ float Bs[128][64];
    int t = threadIdx.x;
    int bx = blockIdx.x, by = blockIdx.y;          // by in [0,4): 2 mats x 2 col-halves
    const float* W    = (by & 2) ? W1 : W0;
    const float* bias = (by & 2) ? b1 : b0;
    int cb = (by & 1) * 64;
    int row0 = bx * 64;

    for (int i = 0; i < 8; ++i) {
        int idx = t + i * 256;
        int r = idx >> 5, k4 = (idx & 31) << 2;
        float4 a = make_float4(0.f, 0.f, 0.f, 0.f);
        if (row0 + r < N_NODES) a = *(const float4*)&A[(size_t)(row0 + r) * 128 + k4];
        *(float4*)&As[r][k4] = a;
    }
    for (int i = 0; i < 8; ++i) {
        int idx = t + i * 256;
        int k = idx >> 4, c4 = (idx & 15) << 2;
        *(float4*)&Bs[k][c4] = *(const float4*)&W[k * 128 + cb + c4];
    }
    __syncthreads();

    int tx = t & 15, ty = t >> 4;
    int rb = ty * 4, cc = tx * 4;
    float acc[4][4] = {};
    for (int k = 0; k < 128; ++k) {
        float a0 = As[rb + 0][k];
        float a1 = As[rb + 1][k];
        float a2 = As[rb + 2][k];
        float a3 = As[rb + 3][k];
        float4 b = *(float4*)&Bs[k][cc];
        acc[0][0] += a0 * b.x; acc[0][1] += a0 * b.y; acc[0][2] += a0 * b.z; acc[0][3] += a0 * b.w;
        acc[1][0] += a1 * b.x; acc[1][1] += a1 * b.y; acc[1][2] += a1 * b.z; acc[1][3] += a1 * b.w;
        acc[2][0] += a2 * b.x; acc[2][1] += a2 * b.y; acc[2][2] += a2 * b.z; acc[2][3] += a2 * b.w;
        acc[3][0] += a3 * b.x; acc[3][1] += a3 * b.y; acc[3][2] += a3 * b.z; acc[3][3] += a3 * b.w;
    }
    float4 bb = *(const float4*)&bias[cb + cc];
    for (int i = 0; i < 4; ++i) {
        int row = row0 + rb + i;
        if (row < N_NODES) {
            float4 o;
            o.x = acc[i][0] + bb.x; o.y = acc[i][1] + bb.y;
            o.z = acc[i][2] + bb.z; o.w = acc[i][3] + bb.w;
            *(float4*)&out[(size_t)row * 256 + by * 64 + cc] = o;
        }
    }
}

// ---------------------------------------------------------------- edge logits
// one wave per edge; buf holds Q (cols 0-127) | K (cols 128-255).
// alpha ~ N(0,1) by construction -> skip segment_max (exp can't overflow;
// ref's +1e-16 on a >=1 denominator is negligible).
__global__ __launch_bounds__(256) void edge_alpha_kernel(
    const float* __restrict__ buf, const int* __restrict__ src,
    const int* __restrict__ dst, float* __restrict__ ex,
    float* __restrict__ denom) {
    int wid = (blockIdx.x * 256 + threadIdx.x) >> 6;
    int lane = threadIdx.x & 63;
    if (wid >= N_EDGES) return;
    int s = src[wid], d = dst[wid];
    float2 q2 = *(const float2*)&buf[(size_t)d * 256 + 2 * lane];
    float2 k2 = *(const float2*)&buf[(size_t)s * 256 + 128 + 2 * lane];
    float p = q2.x * k2.x + q2.y * k2.y;
    p += __shfl_xor(p, 1);
    p += __shfl_xor(p, 2);
    p += __shfl_xor(p, 4);
    p += __shfl_xor(p, 8);
    if ((lane & 15) == 0) {
        int h = lane >> 4;
        float e = expf(p * 0.17677669529663687f);   // 1/sqrt(32)
        ex[(size_t)wid * 4 + h] = e;
        atomicAdd(&denom[d * 4 + h], e);
    }
}

// ---------------------------------------------------------------- aggregate + skip + LN + ReLU
// one wave per node; lane owns channels (2*lane, 2*lane+1); head = lane>>4.
// buf holds V (cols 0-127) | S=skip (cols 128-255).  Writes hout in place.
__global__ __launch_bounds__(256) void agg_ln_kernel(
    const float* __restrict__ buf, const int* __restrict__ src,
    const int* __restrict__ rowptr, const int* __restrict__ eids,
    const float* __restrict__ ex, const float* __restrict__ denom,
    const float* __restrict__ gamma, const float* __restrict__ beta,
    float* __restrict__ hout) {
    int n = (blockIdx.x * 256 + threadIdx.x) >> 6;
    int lane = threadIdx.x & 63;
    if (n >= N_NODES) return;
    int hd = lane >> 4;
    float dinv = 1.0f / (denom[n * 4 + hd] + 1e-16f);
    int e0 = rowptr[n], e1 = rowptr[n + 1];
    float accx = 0.f, accy = 0.f;
    for (int idx = e0; idx < e1; ++idx) {
        int e = eids[idx];
        int s = src[e];
        float w = ex[(size_t)e * 4 + hd] * dinv;
        float2 v2 = *(const float2*)&buf[(size_t)s * 256 + 2 * lane];
        accx += v2.x * w;
        accy += v2.y * w;
    }
    float2 sk = *(const float2*)&buf[(size_t)n * 256 + 128 + 2 * lane];
    float vx = accx + sk.x, vy = accy + sk.y;
    float sum = vx + vy;
    for (int msk = 1; msk < 64; msk <<= 1) sum += __shfl_xor(sum, msk);
    float mu = sum * (1.0f / 128.0f);
    float dx = vx - mu, dy = vy - mu;
    float sq = dx * dx + dy * dy;
    for (int msk = 1; msk < 64; msk <<= 1) sq += __shfl_xor(sq, msk);
    float rs = rsqrtf(sq * (1.0f / 128.0f) + 1e-5f);
    int c = 2 * lane;
    float o0 = dx * rs * gamma[c]     + beta[c];
    float o1 = dy * rs * gamma[c + 1] + beta[c + 1];
    o0 = fmaxf(o0, 0.f);
    o1 = fmaxf(o1, 0.f);
    *(float2*)&hout[(size_t)n * 128 + c] = make_float2(o0, o1);
}

// ---------------------------------------------------------------- classifier
__global__ __launch_bounds__(256) void out_gemm_kernel(
    const float* __restrict__ h, const float* __restrict__ Wout,
    const float* __restrict__ bout, float* __restrict__ out) {
    __shared__ float hs[32][132];
    __shared__ float ws[128 * NCLS_];
    __shared__ float bsd[NCLS_];
    int t = threadIdx.x;
    int n0 = blockIdx.x * 32;
    for (int i = t; i < 128 * NCLS_; i += 256) ws[i] = Wout[i];
    if (t < NCLS_) bsd[t] = bout[t];
    for (int i = t; i < 1024; i += 256) {
        int r = i >> 5, k4 = (i & 31) << 2;
        float4 a = make_float4(0.f, 0.f, 0.f, 0.f);
        if (n0 + r < N_NODES) a = *(const float4*)&h[(size_t)(n0 + r) * 128 + k4];
        *(float4*)&hs[r][k4] = a;
    }
    __syncthreads();
    int r = t >> 3, j0 = (t & 7) * 5;
    float acc[5];
    for (int j = 0; j < 5; ++j) acc[j] = bsd[j0 + j];
    for (int k = 0; k < 128; ++k) {
        float a = hs[r][k];
        for (int j = 0; j < 5; ++j) acc[j] += a * ws[k * NCLS_ + j0 + j];
    }
    int n = n0 + r;
    if (n < N_NODES) {
        for (int j = 0; j < 5; ++j) out[(size_t)n * NCLS_ + j0 + j] = acc[j];
    }
}

// ---------------------------------------------------------------- launch
extern "C" void kernel_launch(void* const* d_in, const int* in_sizes, int n_in,
                              void* d_out, int out_size, void* d_ws, size_t ws_size,
                              hipStream_t stream) {
    const float* x    = (const float*)d_in[0];
    const int*   ei   = (const int*)d_in[1];
    const int*   src  = ei;
    const int*   dst  = ei + N_EDGES;
    const float* Wq   = (const float*)d_in[2];
    const float* bq   = (const float*)d_in[3];
    const float* Wk   = (const float*)d_in[4];
    const float* bk   = (const float*)d_in[5];
    const float* Wv   = (const float*)d_in[6];
    const float* bv   = (const float*)d_in[7];
    const float* Wsk  = (const float*)d_in[8];
    const float* bsk  = (const float*)d_in[9];
    const float* gmm  = (const float*)d_in[10];
    const float* bta  = (const float*)d_in[11];
    const float* Wout = (const float*)d_in[12];
    const float* bout = (const float*)d_in[13];
    float* outp = (float*)d_out;

    char* p = (char*)d_ws;
    auto carve = [&](size_t bytes) {
        char* r = p;
        p += (bytes + 255) & ~(size_t)255;
        return r;
    };
    // total ~189 MB (was ~342 MB — previous round overflowed d_ws)
    float* buf   = (float*)carve((size_t)N_NODES * 256 * 4);  // Q|K then V|S
    float* h     = (float*)carve((size_t)N_NODES * 128 * 4);  // layer out (reused)
    float* exb   = (float*)carve((size_t)N_EDGES * 4 * 4);
    float* denom = (float*)carve((size_t)N_NODES * 4 * 4);
    int* deg     = (int*)carve((size_t)N_NODES * 4);
    int* rowptr  = (int*)carve((size_t)(N_NODES + 1) * 4);
    int* cursor  = (int*)carve((size_t)N_NODES * 4);
    int* eids    = (int*)carve((size_t)N_EDGES * 4);

    // CSR by dst (reused by both layers)
    zero_i32_kernel<<<(N_NODES + 255) / 256, 256, 0, stream>>>(deg, N_NODES);
    hist_kernel<<<2048, 256, 0, stream>>>(dst, deg);
    scan_kernel<<<1, 1024, 0, stream>>>(deg, rowptr);
    copy_kernel<<<512, 256, 0, stream>>>(rowptr, cursor);
    scatter_kernel<<<2048, 256, 0, stream>>>(dst, cursor, eids);

    for (int l = 0; l < 2; ++l) {
        const float* hin = l ? (const float*)h : x;
        zero_f32_kernel<<<(N_NODES * 4 + 255) / 256, 256, 0, stream>>>(denom, N_NODES * 4);
        dim3 g((N_NODES + 63) / 64, 4);
        // Q|K
        gemm_pair_kernel<<<g, 256, 0, stream>>>(
            hin, Wq + l * 16384, Wk + l * 16384, bq + l * 128, bk + l * 128, buf);
        edge_alpha_kernel<<<(N_EDGES + 3) / 4, 256, 0, stream>>>(buf, src, dst, exb, denom);
        // V|S overwrite buf (Q/K dead once exb+denom exist)
        gemm_pair_kernel<<<g, 256, 0, stream>>>(
            hin, Wv + l * 16384, Wsk + l * 16384, bv + l * 128, bsk + l * 128, buf);
        agg_ln_kernel<<<(N_NODES + 3) / 4, 256, 0, stream>>>(
            buf, src, rowptr, eids, exb, denom, gmm + l * 128, bta + l * 128, h);
    }
    out_gemm_kernel<<<(N_NODES + 31) / 32, 256, 0, stream>>>(h, Wout, bout, outp);
}

// Round 3
// 1528.905 us; speedup vs baseline: 1.3523x; 1.3523x over previous
//
#include <hip/hip_runtime.h>
#include <math.h>

#define N_NODES 100000
#define N_EDGES 1600000
#define NCLS_ 40

// ---------------------------------------------------------------- utils
__global__ void zero_i32_kernel(int* __restrict__ p, int n) {
    int i = blockIdx.x * blockDim.x + threadIdx.x;
    if (i < n) p[i] = 0;
}

// ---------------------------------------------------------------- CSR build
__global__ void hist_kernel(const int* __restrict__ dst, int* __restrict__ deg) {
    int i = blockIdx.x * blockDim.x + threadIdx.x;
    int stride = gridDim.x * blockDim.x;
    for (; i < N_EDGES; i += stride) atomicAdd(&deg[dst[i]], 1);
}

__global__ void scan_kernel(const int* __restrict__ deg, int* __restrict__ rowptr) {
    __shared__ int tmp[1024];
    __shared__ int s_off;
    int t = threadIdx.x;
    if (t == 0) s_off = 0;
    __syncthreads();
    for (int base = 0; base < N_NODES; base += 1024) {
        int i = base + t;
        int v = (i < N_NODES) ? deg[i] : 0;
        tmp[t] = v;
        __syncthreads();
        for (int d = 1; d < 1024; d <<= 1) {
            int add = (t >= d) ? tmp[t - d] : 0;
            __syncthreads();
            tmp[t] += add;
            __syncthreads();
        }
        int off = s_off;
        if (i < N_NODES) rowptr[i] = off + tmp[t] - v;   // exclusive
        __syncthreads();
        if (t == 0) s_off = off + tmp[1023];
        __syncthreads();
    }
    if (t == 0) rowptr[N_NODES] = s_off;
}

__global__ void copy_kernel(const int* __restrict__ a, int* __restrict__ b) {
    int i = blockIdx.x * blockDim.x + threadIdx.x;
    int stride = gridDim.x * blockDim.x;
    for (; i < N_NODES; i += stride) b[i] = a[i];
}

// srcs[pos] = src id, CSR(dst)-ordered — removes the eids->src indirection
__global__ void scatter_kernel(const int* __restrict__ src, const int* __restrict__ dst,
                               int* __restrict__ cursor, int* __restrict__ srcs) {
    int i = blockIdx.x * blockDim.x + threadIdx.x;
    int stride = gridDim.x * blockDim.x;
    for (; i < N_EDGES; i += stride) {
        int pos = atomicAdd(&cursor[dst[i]], 1);
        srcs[pos] = src[i];
    }
}

// ---------------------------------------------------------------- paired GEMM
// out[N,256] = A[N,128] @ [W0|W1] + [b0|b1].  64x64 tile, 4x4 micro, fp32 VALU.
__global__ __launch_bounds__(256) void gemm_pair_kernel(
    const float* __restrict__ A,
    const float* __restrict__ W0, const float* __restrict__ W1,
    const float* __restrict__ b0, const float* __restrict__ b1,
    float* __restrict__ out) {
    __shared__ float As[64][132];
    __shared__ float Bs[128][64];
    int t = threadIdx.x;
    int bx = blockIdx.x, by = blockIdx.y;          // by in [0,4): 2 mats x 2 col-halves
    const float* W    = (by & 2) ? W1 : W0;
    const float* bias = (by & 2) ? b1 : b0;
    int cb = (by & 1) * 64;
    int row0 = bx * 64;

    for (int i = 0; i < 8; ++i) {
        int idx = t + i * 256;
        int r = idx >> 5, k4 = (idx & 31) << 2;
        float4 a = make_float4(0.f, 0.f, 0.f, 0.f);
        if (row0 + r < N_NODES) a = *(const float4*)&A[(size_t)(row0 + r) * 128 + k4];
        *(float4*)&As[r][k4] = a;
    }
    for (int i = 0; i < 8; ++i) {
        int idx = t + i * 256;
        int k = idx >> 4, c4 = (idx & 15) << 2;
        *(float4*)&Bs[k][c4] = *(const float4*)&W[k * 128 + cb + c4];
    }
    __syncthreads();

    int tx = t & 15, ty = t >> 4;
    int rb = ty * 4, cc = tx * 4;
    float acc[4][4] = {};
    for (int k = 0; k < 128; ++k) {
        float a0 = As[rb + 0][k];
        float a1 = As[rb + 1][k];
        float a2 = As[rb + 2][k];
        float a3 = As[rb + 3][k];
        float4 b = *(float4*)&Bs[k][cc];
        acc[0][0] += a0 * b.x; acc[0][1] += a0 * b.y; acc[0][2] += a0 * b.z; acc[0][3] += a0 * b.w;
        acc[1][0] += a1 * b.x; acc[1][1] += a1 * b.y; acc[1][2] += a1 * b.z; acc[1][3] += a1 * b.w;
        acc[2][0] += a2 * b.x; acc[2][1] += a2 * b.y; acc[2][2] += a2 * b.z; acc[2][3] += a2 * b.w;
        acc[3][0] += a3 * b.x; acc[3][1] += a3 * b.y; acc[3][2] += a3 * b.z; acc[3][3] += a3 * b.w;
    }
    float4 bb = *(const float4*)&bias[cb + cc];
    for (int i = 0; i < 4; ++i) {
        int row = row0 + rb + i;
        if (row < N_NODES) {
            float4 o;
            o.x = acc[i][0] + bb.x; o.y = acc[i][1] + bb.y;
            o.z = acc[i][2] + bb.z; o.w = acc[i][3] + bb.w;
            *(float4*)&out[(size_t)row * 256 + by * 64 + cc] = o;
        }
    }
}

// ---------------------------------------------------------------- attention logits (CSR form)
// One wave per dst node. Q[n] loaded once into regs; iterate incoming edges
// gathering K[src]. ex stored CSR-ordered; denom written once (no atomics).
// No segment-max: alpha ~ N(0,1) by construction, exp can't overflow.
__global__ __launch_bounds__(256) void alpha_csr_kernel(
    const float* __restrict__ buf,           // Q (cols 0-127) | K (cols 128-255)
    const int* __restrict__ srcs, const int* __restrict__ rowptr,
    float* __restrict__ ex, float* __restrict__ denom) {
    int n = (blockIdx.x * 256 + threadIdx.x) >> 6;
    int lane = threadIdx.x & 63;
    if (n >= N_NODES) return;
    int hd = lane >> 4;
    float2 q2 = *(const float2*)&buf[(size_t)n * 256 + 2 * lane];
    int e0 = rowptr[n], e1 = rowptr[n + 1];
    float dsum = 0.f;
    const float sc = 0.17677669529663687f;   // 1/sqrt(32)
    int idx = e0;
    for (; idx + 1 < e1; idx += 2) {
        int s0 = srcs[idx], s1 = srcs[idx + 1];
        float2 k0 = *(const float2*)&buf[(size_t)s0 * 256 + 128 + 2 * lane];
        float2 k1 = *(const float2*)&buf[(size_t)s1 * 256 + 128 + 2 * lane];
        float p0 = q2.x * k0.x + q2.y * k0.y;
        float p1 = q2.x * k1.x + q2.y * k1.y;
        p0 += __shfl_xor(p0, 1); p1 += __shfl_xor(p1, 1);
        p0 += __shfl_xor(p0, 2); p1 += __shfl_xor(p1, 2);
        p0 += __shfl_xor(p0, 4); p1 += __shfl_xor(p1, 4);
        p0 += __shfl_xor(p0, 8); p1 += __shfl_xor(p1, 8);
        float e0v = expf(p0 * sc);
        float e1v = expf(p1 * sc);
        if ((lane & 15) == 0) {
            ex[(size_t)idx * 4 + hd] = e0v;
            ex[(size_t)(idx + 1) * 4 + hd] = e1v;
            dsum += e0v + e1v;
        }
    }
    if (idx < e1) {
        int s0 = srcs[idx];
        float2 k0 = *(const float2*)&buf[(size_t)s0 * 256 + 128 + 2 * lane];
        float p0 = q2.x * k0.x + q2.y * k0.y;
        p0 += __shfl_xor(p0, 1);
        p0 += __shfl_xor(p0, 2);
        p0 += __shfl_xor(p0, 4);
        p0 += __shfl_xor(p0, 8);
        float e0v = expf(p0 * sc);
        if ((lane & 15) == 0) {
            ex[(size_t)idx * 4 + hd] = e0v;
            dsum += e0v;
        }
    }
    if ((lane & 15) == 0) denom[n * 4 + hd] = dsum;
}

// ---------------------------------------------------------------- aggregate + skip + LN + ReLU
// One wave per node; lane owns channels (2*lane, 2*lane+1); head = lane>>4.
// buf holds V (cols 0-127) | S=skip (cols 128-255).
__global__ __launch_bounds__(256) void agg_ln_kernel(
    const float* __restrict__ buf, const int* __restrict__ srcs,
    const int* __restrict__ rowptr,
    const float* __restrict__ ex, const float* __restrict__ denom,
    const float* __restrict__ gamma, const float* __restrict__ beta,
    float* __restrict__ hout) {
    int n = (blockIdx.x * 256 + threadIdx.x) >> 6;
    int lane = threadIdx.x & 63;
    if (n >= N_NODES) return;
    int hd = lane >> 4;
    float dinv = 1.0f / (denom[n * 4 + hd] + 1e-16f);
    int e0 = rowptr[n], e1 = rowptr[n + 1];
    float accx = 0.f, accy = 0.f;
    int idx = e0;
    for (; idx + 1 < e1; idx += 2) {
        int s0 = srcs[idx], s1 = srcs[idx + 1];
        float w0 = ex[(size_t)idx * 4 + hd];
        float w1 = ex[(size_t)(idx + 1) * 4 + hd];
        float2 v0 = *(const float2*)&buf[(size_t)s0 * 256 + 2 * lane];
        float2 v1 = *(const float2*)&buf[(size_t)s1 * 256 + 2 * lane];
        accx += v0.x * w0 + v1.x * w1;
        accy += v0.y * w0 + v1.y * w1;
    }
    if (idx < e1) {
        int s0 = srcs[idx];
        float w0 = ex[(size_t)idx * 4 + hd];
        float2 v0 = *(const float2*)&buf[(size_t)s0 * 256 + 2 * lane];
        accx += v0.x * w0;
        accy += v0.y * w0;
    }
    accx *= dinv;
    accy *= dinv;
    float2 sk = *(const float2*)&buf[(size_t)n * 256 + 128 + 2 * lane];
    float vx = accx + sk.x, vy = accy + sk.y;
    float sum = vx + vy;
    for (int msk = 1; msk < 64; msk <<= 1) sum += __shfl_xor(sum, msk);
    float mu = sum * (1.0f / 128.0f);
    float dx = vx - mu, dy = vy - mu;
    float sq = dx * dx + dy * dy;
    for (int msk = 1; msk < 64; msk <<= 1) sq += __shfl_xor(sq, msk);
    float rs = rsqrtf(sq * (1.0f / 128.0f) + 1e-5f);
    int c = 2 * lane;
    float o0 = dx * rs * gamma[c]     + beta[c];
    float o1 = dy * rs * gamma[c + 1] + beta[c + 1];
    o0 = fmaxf(o0, 0.f);
    o1 = fmaxf(o1, 0.f);
    *(float2*)&hout[(size_t)n * 128 + c] = make_float2(o0, o1);
}

// ---------------------------------------------------------------- classifier
__global__ __launch_bounds__(256) void out_gemm_kernel(
    const float* __restrict__ h, const float* __restrict__ Wout,
    const float* __restrict__ bout, float* __restrict__ out) {
    __shared__ float hs[32][132];
    __shared__ float ws[128 * NCLS_];
    __shared__ float bsd[NCLS_];
    int t = threadIdx.x;
    int n0 = blockIdx.x * 32;
    for (int i = t; i < 128 * NCLS_; i += 256) ws[i] = Wout[i];
    if (t < NCLS_) bsd[t] = bout[t];
    for (int i = t; i < 1024; i += 256) {
        int r = i >> 5, k4 = (i & 31) << 2;
        float4 a = make_float4(0.f, 0.f, 0.f, 0.f);
        if (n0 + r < N_NODES) a = *(const float4*)&h[(size_t)(n0 + r) * 128 + k4];
        *(float4*)&hs[r][k4] = a;
    }
    __syncthreads();
    int r = t >> 3, j0 = (t & 7) * 5;
    float acc[5];
    for (int j = 0; j < 5; ++j) acc[j] = bsd[j0 + j];
    for (int k = 0; k < 128; ++k) {
        float a = hs[r][k];
        for (int j = 0; j < 5; ++j) acc[j] += a * ws[k * NCLS_ + j0 + j];
    }
    int n = n0 + r;
    if (n < N_NODES) {
        for (int j = 0; j < 5; ++j) out[(size_t)n * NCLS_ + j0 + j] = acc[j];
    }
}

// ---------------------------------------------------------------- launch
extern "C" void kernel_launch(void* const* d_in, const int* in_sizes, int n_in,
                              void* d_out, int out_size, void* d_ws, size_t ws_size,
                              hipStream_t stream) {
    const float* x    = (const float*)d_in[0];
    const int*   ei   = (const int*)d_in[1];
    const int*   src  = ei;
    const int*   dst  = ei + N_EDGES;
    const float* Wq   = (const float*)d_in[2];
    const float* bq   = (const float*)d_in[3];
    const float* Wk   = (const float*)d_in[4];
    const float* bk   = (const float*)d_in[5];
    const float* Wv   = (const float*)d_in[6];
    const float* bv   = (const float*)d_in[7];
    const float* Wsk  = (const float*)d_in[8];
    const float* bsk  = (const float*)d_in[9];
    const float* gmm  = (const float*)d_in[10];
    const float* bta  = (const float*)d_in[11];
    const float* Wout = (const float*)d_in[12];
    const float* bout = (const float*)d_in[13];
    float* outp = (float*)d_out;

    char* p = (char*)d_ws;
    auto carve = [&](size_t bytes) {
        char* r = p;
        p += (bytes + 255) & ~(size_t)255;
        return r;
    };
    float* buf   = (float*)carve((size_t)N_NODES * 256 * 4);  // Q|K then V|S
    float* h     = (float*)carve((size_t)N_NODES * 128 * 4);  // layer out (reused)
    float* exb   = (float*)carve((size_t)N_EDGES * 4 * 4);    // CSR-ordered ex
    float* denom = (float*)carve((size_t)N_NODES * 4 * 4);
    int* deg     = (int*)carve((size_t)N_NODES * 4);
    int* rowptr  = (int*)carve((size_t)(N_NODES + 1) * 4);
    int* cursor  = (int*)carve((size_t)N_NODES * 4);
    int* srcs    = (int*)carve((size_t)N_EDGES * 4);          // CSR-ordered src ids

    // CSR by dst (reused by both layers)
    zero_i32_kernel<<<(N_NODES + 255) / 256, 256, 0, stream>>>(deg, N_NODES);
    hist_kernel<<<2048, 256, 0, stream>>>(dst, deg);
    scan_kernel<<<1, 1024, 0, stream>>>(deg, rowptr);
    copy_kernel<<<512, 256, 0, stream>>>(rowptr, cursor);
    scatter_kernel<<<2048, 256, 0, stream>>>(src, dst, cursor, srcs);

    for (int l = 0; l < 2; ++l) {
        const float* hin = l ? (const float*)h : x;
        dim3 g((N_NODES + 63) / 64, 4);
        // Q|K
        gemm_pair_kernel<<<g, 256, 0, stream>>>(
            hin, Wq + l * 16384, Wk + l * 16384, bq + l * 128, bk + l * 128, buf);
        alpha_csr_kernel<<<(N_NODES + 3) / 4, 256, 0, stream>>>(buf, srcs, rowptr, exb, denom);
        // V|S overwrite buf (Q/K dead once exb+denom exist)
        gemm_pair_kernel<<<g, 256, 0, stream>>>(
            hin, Wv + l * 16384, Wsk + l * 16384, bv + l * 128, bsk + l * 128, buf);
        agg_ln_kernel<<<(N_NODES + 3) / 4, 256, 0, stream>>>(
            buf, srcs, rowptr, exb, denom, gmm + l * 128, bta + l * 128, h);
    }
    out_gemm_kernel<<<(N_NODES + 31) / 32, 256, 0, stream>>>(h, Wout, bout, outp);
}

// Round 4
// 1270.347 us; speedup vs baseline: 1.6276x; 1.2035x over previous
//
#include <hip/hip_runtime.h>
#include <math.h>

#define N_NODES 100000
#define N_EDGES 1600000
#define NCLS_ 40
#define NSCAN_BLOCKS ((N_NODES + 1023) / 1024)   // 98

// ---------------------------------------------------------------- utils
__global__ void zero_i32_kernel(int* __restrict__ p, int n) {
    int i = blockIdx.x * blockDim.x + threadIdx.x;
    if (i < n) p[i] = 0;
}

// ---------------------------------------------------------------- CSR build
__global__ void hist_kernel(const int* __restrict__ dst, int* __restrict__ deg) {
    int i = blockIdx.x * blockDim.x + threadIdx.x;
    int stride = gridDim.x * blockDim.x;
    for (; i < N_EDGES; i += stride) atomicAdd(&deg[dst[i]], 1);
}

// phase 1: per-block exclusive partials + block sums (98 parallel blocks)
__global__ __launch_bounds__(1024) void scan_block_kernel(
    const int* __restrict__ deg, int* __restrict__ rowptr, int* __restrict__ sums) {
    __shared__ int tmp[1024];
    int t = threadIdx.x;
    int i = blockIdx.x * 1024 + t;
    int v = (i < N_NODES) ? deg[i] : 0;
    tmp[t] = v;
    __syncthreads();
    for (int d = 1; d < 1024; d <<= 1) {
        int add = (t >= d) ? tmp[t - d] : 0;
        __syncthreads();
        tmp[t] += add;
        __syncthreads();
    }
    if (i < N_NODES) rowptr[i] = tmp[t] - v;           // within-block exclusive
    if (t == 1023) sums[blockIdx.x] = tmp[1023];       // block total
}

// phase 2: exclusive scan of the 98 block sums (single tiny block)
__global__ __launch_bounds__(128) void scan_sums_kernel(int* __restrict__ sums) {
    __shared__ int tmp[128];
    int t = threadIdx.x;
    int v = (t < NSCAN_BLOCKS) ? sums[t] : 0;
    tmp[t] = v;
    __syncthreads();
    for (int d = 1; d < 128; d <<= 1) {
        int add = (t >= d) ? tmp[t - d] : 0;
        __syncthreads();
        tmp[t] += add;
        __syncthreads();
    }
    if (t < NSCAN_BLOCKS) sums[t] = tmp[t] - v;        // exclusive
}

// phase 3: add block offset; emit rowptr AND cursor (absorbs copy_kernel)
__global__ void scan_add_kernel(int* __restrict__ rowptr, const int* __restrict__ sums,
                                int* __restrict__ cursor) {
    int i = blockIdx.x * blockDim.x + threadIdx.x;
    if (i < N_NODES) {
        int val = rowptr[i] + sums[i >> 10];
        rowptr[i] = val;
        cursor[i] = val;
    }
    if (i == 0) rowptr[N_NODES] = N_EDGES;             // all dst < N ⇒ total = E
}

// srcs[pos] = src id, CSR(dst)-ordered — removes the eids->src indirection
__global__ void scatter_kernel(const int* __restrict__ src, const int* __restrict__ dst,
                               int* __restrict__ cursor, int* __restrict__ srcs) {
    int i = blockIdx.x * blockDim.x + threadIdx.x;
    int stride = gridDim.x * blockDim.x;
    for (; i < N_EDGES; i += stride) {
        int pos = atomicAdd(&cursor[dst[i]], 1);
        srcs[pos] = src[i];
    }
}

// ---------------------------------------------------------------- paired GEMM
// out[N,256] = A[N,128] @ [W0|W1] + [b0|b1].  64x64 tile, 4x4 micro, fp32 VALU.
__global__ __launch_bounds__(256) void gemm_pair_kernel(
    const float* __restrict__ A,
    const float* __restrict__ W0, const float* __restrict__ W1,
    const float* __restrict__ b0, const float* __restrict__ b1,
    float* __restrict__ out) {
    __shared__ float As[64][132];
    __shared__ float Bs[128][64];
    int t = threadIdx.x;
    int bx = blockIdx.x, by = blockIdx.y;          // by in [0,4): 2 mats x 2 col-halves
    const float* W    = (by & 2) ? W1 : W0;
    const float* bias = (by & 2) ? b1 : b0;
    int cb = (by & 1) * 64;
    int row0 = bx * 64;

    for (int i = 0; i < 8; ++i) {
        int idx = t + i * 256;
        int r = idx >> 5, k4 = (idx & 31) << 2;
        float4 a = make_float4(0.f, 0.f, 0.f, 0.f);
        if (row0 + r < N_NODES) a = *(const float4*)&A[(size_t)(row0 + r) * 128 + k4];
        *(float4*)&As[r][k4] = a;
    }
    for (int i = 0; i < 8; ++i) {
        int idx = t + i * 256;
        int k = idx >> 4, c4 = (idx & 15) << 2;
        *(float4*)&Bs[k][c4] = *(const float4*)&W[k * 128 + cb + c4];
    }
    __syncthreads();

    int tx = t & 15, ty = t >> 4;
    int rb = ty * 4, cc = tx * 4;
    float acc[4][4] = {};
    for (int k = 0; k < 128; ++k) {
        float a0 = As[rb + 0][k];
        float a1 = As[rb + 1][k];
        float a2 = As[rb + 2][k];
        float a3 = As[rb + 3][k];
        float4 b = *(float4*)&Bs[k][cc];
        acc[0][0] += a0 * b.x; acc[0][1] += a0 * b.y; acc[0][2] += a0 * b.z; acc[0][3] += a0 * b.w;
        acc[1][0] += a1 * b.x; acc[1][1] += a1 * b.y; acc[1][2] += a1 * b.z; acc[1][3] += a1 * b.w;
        acc[2][0] += a2 * b.x; acc[2][1] += a2 * b.y; acc[2][2] += a2 * b.z; acc[2][3] += a2 * b.w;
        acc[3][0] += a3 * b.x; acc[3][1] += a3 * b.y; acc[3][2] += a3 * b.z; acc[3][3] += a3 * b.w;
    }
    float4 bb = *(const float4*)&bias[cb + cc];
    for (int i = 0; i < 4; ++i) {
        int row = row0 + rb + i;
        if (row < N_NODES) {
            float4 o;
            o.x = acc[i][0] + bb.x; o.y = acc[i][1] + bb.y;
            o.z = acc[i][2] + bb.z; o.w = acc[i][3] + bb.w;
            *(float4*)&out[(size_t)row * 256 + by * 64 + cc] = o;
        }
    }
}

// ---------------------------------------------------------------- attention logits (CSR form)
// One wave per dst node; Q[n] in regs; 4x-unrolled K[src] gathers (latency-bound:
// more outstanding loads per wave). ex CSR-ordered; denom register-accumulated.
__global__ __launch_bounds__(256) void alpha_csr_kernel(
    const float* __restrict__ buf,           // Q (cols 0-127) | K (cols 128-255)
    const int* __restrict__ srcs, const int* __restrict__ rowptr,
    float* __restrict__ ex, float* __restrict__ denom) {
    int n = (blockIdx.x * 256 + threadIdx.x) >> 6;
    int lane = threadIdx.x & 63;
    if (n >= N_NODES) return;
    int hd = lane >> 4;
    float2 q2 = *(const float2*)&buf[(size_t)n * 256 + 2 * lane];
    int e0 = rowptr[n], e1 = rowptr[n + 1];
    float dsum = 0.f;
    const float sc = 0.17677669529663687f;   // 1/sqrt(32)
    int idx = e0;
    for (; idx + 3 < e1; idx += 4) {
        int s0 = srcs[idx], s1 = srcs[idx + 1], s2 = srcs[idx + 2], s3 = srcs[idx + 3];
        float2 k0 = *(const float2*)&buf[(size_t)s0 * 256 + 128 + 2 * lane];
        float2 k1 = *(const float2*)&buf[(size_t)s1 * 256 + 128 + 2 * lane];
        float2 k2 = *(const float2*)&buf[(size_t)s2 * 256 + 128 + 2 * lane];
        float2 k3 = *(const float2*)&buf[(size_t)s3 * 256 + 128 + 2 * lane];
        float p0 = q2.x * k0.x + q2.y * k0.y;
        float p1 = q2.x * k1.x + q2.y * k1.y;
        float p2 = q2.x * k2.x + q2.y * k2.y;
        float p3 = q2.x * k3.x + q2.y * k3.y;
        p0 += __shfl_xor(p0, 1); p1 += __shfl_xor(p1, 1); p2 += __shfl_xor(p2, 1); p3 += __shfl_xor(p3, 1);
        p0 += __shfl_xor(p0, 2); p1 += __shfl_xor(p1, 2); p2 += __shfl_xor(p2, 2); p3 += __shfl_xor(p3, 2);
        p0 += __shfl_xor(p0, 4); p1 += __shfl_xor(p1, 4); p2 += __shfl_xor(p2, 4); p3 += __shfl_xor(p3, 4);
        p0 += __shfl_xor(p0, 8); p1 += __shfl_xor(p1, 8); p2 += __shfl_xor(p2, 8); p3 += __shfl_xor(p3, 8);
        float e0v = expf(p0 * sc), e1v = expf(p1 * sc);
        float e2v = expf(p2 * sc), e3v = expf(p3 * sc);
        if ((lane & 15) == 0) {
            ex[(size_t)idx * 4 + hd]       = e0v;
            ex[(size_t)(idx + 1) * 4 + hd] = e1v;
            ex[(size_t)(idx + 2) * 4 + hd] = e2v;
            ex[(size_t)(idx + 3) * 4 + hd] = e3v;
            dsum += (e0v + e1v) + (e2v + e3v);
        }
    }
    for (; idx < e1; ++idx) {
        int s0 = srcs[idx];
        float2 k0 = *(const float2*)&buf[(size_t)s0 * 256 + 128 + 2 * lane];
        float p0 = q2.x * k0.x + q2.y * k0.y;
        p0 += __shfl_xor(p0, 1);
        p0 += __shfl_xor(p0, 2);
        p0 += __shfl_xor(p0, 4);
        p0 += __shfl_xor(p0, 8);
        float e0v = expf(p0 * sc);
        if ((lane & 15) == 0) {
            ex[(size_t)idx * 4 + hd] = e0v;
            dsum += e0v;
        }
    }
    if ((lane & 15) == 0) denom[n * 4 + hd] = dsum;
}

// ---------------------------------------------------------------- aggregate + skip + LN + ReLU
// One wave per node; lane owns channels (2*lane, 2*lane+1); head = lane>>4.
// buf holds V (cols 0-127) | S=skip (cols 128-255).  4x-unrolled gathers.
__global__ __launch_bounds__(256) void agg_ln_kernel(
    const float* __restrict__ buf, const int* __restrict__ srcs,
    const int* __restrict__ rowptr,
    const float* __restrict__ ex, const float* __restrict__ denom,
    const float* __restrict__ gamma, const float* __restrict__ beta,
    float* __restrict__ hout) {
    int n = (blockIdx.x * 256 + threadIdx.x) >> 6;
    int lane = threadIdx.x & 63;
    if (n >= N_NODES) return;
    int hd = lane >> 4;
    float dinv = 1.0f / (denom[n * 4 + hd] + 1e-16f);
    int e0 = rowptr[n], e1 = rowptr[n + 1];
    float accx = 0.f, accy = 0.f;
    int idx = e0;
    for (; idx + 3 < e1; idx += 4) {
        int s0 = srcs[idx], s1 = srcs[idx + 1], s2 = srcs[idx + 2], s3 = srcs[idx + 3];
        float w0 = ex[(size_t)idx * 4 + hd];
        float w1 = ex[(size_t)(idx + 1) * 4 + hd];
        float w2 = ex[(size_t)(idx + 2) * 4 + hd];
        float w3 = ex[(size_t)(idx + 3) * 4 + hd];
        float2 v0 = *(const float2*)&buf[(size_t)s0 * 256 + 2 * lane];
        float2 v1 = *(const float2*)&buf[(size_t)s1 * 256 + 2 * lane];
        float2 v2 = *(const float2*)&buf[(size_t)s2 * 256 + 2 * lane];
        float2 v3 = *(const float2*)&buf[(size_t)s3 * 256 + 2 * lane];
        accx += v0.x * w0 + v1.x * w1 + v2.x * w2 + v3.x * w3;
        accy += v0.y * w0 + v1.y * w1 + v2.y * w2 + v3.y * w3;
    }
    for (; idx < e1; ++idx) {
        int s0 = srcs[idx];
        float w0 = ex[(size_t)idx * 4 + hd];
        float2 v0 = *(const float2*)&buf[(size_t)s0 * 256 + 2 * lane];
        accx += v0.x * w0;
        accy += v0.y * w0;
    }
    accx *= dinv;
    accy *= dinv;
    float2 sk = *(const float2*)&buf[(size_t)n * 256 + 128 + 2 * lane];
    float vx = accx + sk.x, vy = accy + sk.y;
    float sum = vx + vy;
    for (int msk = 1; msk < 64; msk <<= 1) sum += __shfl_xor(sum, msk);
    float mu = sum * (1.0f / 128.0f);
    float dx = vx - mu, dy = vy - mu;
    float sq = dx * dx + dy * dy;
    for (int msk = 1; msk < 64; msk <<= 1) sq += __shfl_xor(sq, msk);
    float rs = rsqrtf(sq * (1.0f / 128.0f) + 1e-5f);
    int c = 2 * lane;
    float o0 = dx * rs * gamma[c]     + beta[c];
    float o1 = dy * rs * gamma[c + 1] + beta[c + 1];
    o0 = fmaxf(o0, 0.f);
    o1 = fmaxf(o1, 0.f);
    *(float2*)&hout[(size_t)n * 128 + c] = make_float2(o0, o1);
}

// ---------------------------------------------------------------- classifier
__global__ __launch_bounds__(256) void out_gemm_kernel(
    const float* __restrict__ h, const float* __restrict__ Wout,
    const float* __restrict__ bout, float* __restrict__ out) {
    __shared__ float hs[32][132];
    __shared__ float ws[128 * NCLS_];
    __shared__ float bsd[NCLS_];
    int t = threadIdx.x;
    int n0 = blockIdx.x * 32;
    for (int i = t; i < 128 * NCLS_; i += 256) ws[i] = Wout[i];
    if (t < NCLS_) bsd[t] = bout[t];
    for (int i = t; i < 1024; i += 256) {
        int r = i >> 5, k4 = (i & 31) << 2;
        float4 a = make_float4(0.f, 0.f, 0.f, 0.f);
        if (n0 + r < N_NODES) a = *(const float4*)&h[(size_t)(n0 + r) * 128 + k4];
        *(float4*)&hs[r][k4] = a;
    }
    __syncthreads();
    int r = t >> 3, j0 = (t & 7) * 5;
    float acc[5];
    for (int j = 0; j < 5; ++j) acc[j] = bsd[j0 + j];
    for (int k = 0; k < 128; ++k) {
        float a = hs[r][k];
        for (int j = 0; j < 5; ++j) acc[j] += a * ws[k * NCLS_ + j0 + j];
    }
    int n = n0 + r;
    if (n < N_NODES) {
        for (int j = 0; j < 5; ++j) out[(size_t)n * NCLS_ + j0 + j] = acc[j];
    }
}

// ---------------------------------------------------------------- launch
extern "C" void kernel_launch(void* const* d_in, const int* in_sizes, int n_in,
                              void* d_out, int out_size, void* d_ws, size_t ws_size,
                              hipStream_t stream) {
    const float* x    = (const float*)d_in[0];
    const int*   ei   = (const int*)d_in[1];
    const int*   src  = ei;
    const int*   dst  = ei + N_EDGES;
    const float* Wq   = (const float*)d_in[2];
    const float* bq   = (const float*)d_in[3];
    const float* Wk   = (const float*)d_in[4];
    const float* bk   = (const float*)d_in[5];
    const float* Wv   = (const float*)d_in[6];
    const float* bv   = (const float*)d_in[7];
    const float* Wsk  = (const float*)d_in[8];
    const float* bsk  = (const float*)d_in[9];
    const float* gmm  = (const float*)d_in[10];
    const float* bta  = (const float*)d_in[11];
    const float* Wout = (const float*)d_in[12];
    const float* bout = (const float*)d_in[13];
    float* outp = (float*)d_out;

    char* p = (char*)d_ws;
    auto carve = [&](size_t bytes) {
        char* r = p;
        p += (bytes + 255) & ~(size_t)255;
        return r;
    };
    float* buf   = (float*)carve((size_t)N_NODES * 256 * 4);  // Q|K then V|S
    float* h     = (float*)carve((size_t)N_NODES * 128 * 4);  // layer out (reused)
    float* exb   = (float*)carve((size_t)N_EDGES * 4 * 4);    // CSR-ordered ex
    float* denom = (float*)carve((size_t)N_NODES * 4 * 4);
    int* deg     = (int*)carve((size_t)N_NODES * 4);
    int* rowptr  = (int*)carve((size_t)(N_NODES + 1) * 4);
    int* cursor  = (int*)carve((size_t)N_NODES * 4);
    int* srcs    = (int*)carve((size_t)N_EDGES * 4);          // CSR-ordered src ids
    int* sums    = (int*)carve((size_t)NSCAN_BLOCKS * 4);

    // CSR by dst (reused by both layers) — hierarchical parallel scan
    zero_i32_kernel<<<(N_NODES + 255) / 256, 256, 0, stream>>>(deg, N_NODES);
    hist_kernel<<<2048, 256, 0, stream>>>(dst, deg);
    scan_block_kernel<<<NSCAN_BLOCKS, 1024, 0, stream>>>(deg, rowptr, sums);
    scan_sums_kernel<<<1, 128, 0, stream>>>(sums);
    scan_add_kernel<<<(N_NODES + 255) / 256, 256, 0, stream>>>(rowptr, sums, cursor);
    scatter_kernel<<<2048, 256, 0, stream>>>(src, dst, cursor, srcs);

    for (int l = 0; l < 2; ++l) {
        const float* hin = l ? (const float*)h : x;
        dim3 g((N_NODES + 63) / 64, 4);
        // Q|K
        gemm_pair_kernel<<<g, 256, 0, stream>>>(
            hin, Wq + l * 16384, Wk + l * 16384, bq + l * 128, bk + l * 128, buf);
        alpha_csr_kernel<<<(N_NODES + 3) / 4, 256, 0, stream>>>(buf, srcs, rowptr, exb, denom);
        // V|S overwrite buf (Q/K dead once exb+denom exist)
        gemm_pair_kernel<<<g, 256, 0, stream>>>(
            hin, Wv + l * 16384, Wsk + l * 16384, bv + l * 128, bsk + l * 128, buf);
        agg_ln_kernel<<<(N_NODES + 3) / 4, 256, 0, stream>>>(
            buf, srcs, rowptr, exb, denom, gmm + l * 128, bta + l * 128, h);
    }
    out_gemm_kernel<<<(N_NODES + 31) / 32, 256, 0, stream>>>(h, Wout, bout, outp);
}

// Round 5
// 1230.283 us; speedup vs baseline: 1.6806x; 1.0326x over previous
//
#include <hip/hip_runtime.h>
#include <math.h>

#define N_NODES 100000
#define N_EDGES 1600000
#define NCLS_ 40
#define NSCAN_BLOCKS ((N_NODES + 1023) / 1024)   // 98
#define DRANGE 12500                              // N_NODES / 8 XCD groups

// ---------------------------------------------------------------- utils
__global__ void zero_i32_kernel(int* __restrict__ p, int n) {
    int i = blockIdx.x * blockDim.x + threadIdx.x;
    if (i < n) p[i] = 0;
}

// ---------------------------------------------------------------- CSR build
// XCD-localized histogram: block-group g (blockIdx&7 -> XCD g under the
// round-robin dispatch heuristic) handles only dst in [g*DRANGE,(g+1)*DRANGE).
// Each group's 50 KB deg slice stays in its own XCD L2 -> no cross-XCD line
// ping. dst[] is read 8x but is L3-resident (6.4 MB << 256 MB).
__global__ __launch_bounds__(256) void hist_kernel(
    const int* __restrict__ dst, int* __restrict__ deg) {
    int group = blockIdx.x & 7;
    int gblk  = blockIdx.x >> 3;
    int nblk  = gridDim.x >> 3;
    int lo = group * DRANGE, hi = lo + DRANGE;
    for (int i = gblk * 256 + threadIdx.x; i < N_EDGES; i += nblk * 256) {
        int d = dst[i];
        if (d >= lo && d < hi) atomicAdd(&deg[d], 1);
    }
}

// phase 1: per-block exclusive partials + block sums (98 parallel blocks)
__global__ __launch_bounds__(1024) void scan_block_kernel(
    const int* __restrict__ deg, int* __restrict__ rowptr, int* __restrict__ sums) {
    __shared__ int tmp[1024];
    int t = threadIdx.x;
    int i = blockIdx.x * 1024 + t;
    int v = (i < N_NODES) ? deg[i] : 0;
    tmp[t] = v;
    __syncthreads();
    for (int d = 1; d < 1024; d <<= 1) {
        int add = (t >= d) ? tmp[t - d] : 0;
        __syncthreads();
        tmp[t] += add;
        __syncthreads();
    }
    if (i < N_NODES) rowptr[i] = tmp[t] - v;           // within-block exclusive
    if (t == 1023) sums[blockIdx.x] = tmp[1023];       // block total
}

// phase 2: exclusive scan of the 98 block sums (single tiny block)
__global__ __launch_bounds__(128) void scan_sums_kernel(int* __restrict__ sums) {
    __shared__ int tmp[128];
    int t = threadIdx.x;
    int v = (t < NSCAN_BLOCKS) ? sums[t] : 0;
    tmp[t] = v;
    __syncthreads();
    for (int d = 1; d < 128; d <<= 1) {
        int add = (t >= d) ? tmp[t - d] : 0;
        __syncthreads();
        tmp[t] += add;
        __syncthreads();
    }
    if (t < NSCAN_BLOCKS) sums[t] = tmp[t] - v;        // exclusive
}

// phase 3: add block offset; emit rowptr AND cursor
__global__ void scan_add_kernel(int* __restrict__ rowptr, const int* __restrict__ sums,
                                int* __restrict__ cursor) {
    int i = blockIdx.x * blockDim.x + threadIdx.x;
    if (i < N_NODES) {
        int val = rowptr[i] + sums[i >> 10];
        rowptr[i] = val;
        cursor[i] = val;
    }
    if (i == 0) rowptr[N_NODES] = N_EDGES;             // all dst < N ⇒ total = E
}

// XCD-localized scatter: same dst-range filter as hist. Each group's srcs
// write window (~800 KB) + cursor slice live in one XCD's L2, so the 16
// writes per cache line coalesce before eviction (R4: 107 MB HBM writes for
// a 6.4 MB array = 64 B line flushed per 4 B write).
__global__ __launch_bounds__(256) void scatter_kernel(
    const int* __restrict__ src, const int* __restrict__ dst,
    int* __restrict__ cursor, int* __restrict__ srcs) {
    int group = blockIdx.x & 7;
    int gblk  = blockIdx.x >> 3;
    int nblk  = gridDim.x >> 3;
    int lo = group * DRANGE, hi = lo + DRANGE;
    for (int i = gblk * 256 + threadIdx.x; i < N_EDGES; i += nblk * 256) {
        int d = dst[i];
        if (d >= lo && d < hi) {
            int pos = atomicAdd(&cursor[d], 1);
            srcs[pos] = src[i];
        }
    }
}

// ---------------------------------------------------------------- paired GEMM
// out[N,256] = A[N,128] @ [W0|W1] + [b0|b1].  64x64 tile, 4x4 micro, fp32 VALU.
__global__ __launch_bounds__(256) void gemm_pair_kernel(
    const float* __restrict__ A,
    const float* __restrict__ W0, const float* __restrict__ W1,
    const float* __restrict__ b0, const float* __restrict__ b1,
    float* __restrict__ out) {
    __shared__ float As[64][132];
    __shared__ float Bs[128][64];
    int t = threadIdx.x;
    int bx = blockIdx.x, by = blockIdx.y;          // by in [0,4): 2 mats x 2 col-halves
    const float* W    = (by & 2) ? W1 : W0;
    const float* bias = (by & 2) ? b1 : b0;
    int cb = (by & 1) * 64;
    int row0 = bx * 64;

    for (int i = 0; i < 8; ++i) {
        int idx = t + i * 256;
        int r = idx >> 5, k4 = (idx & 31) << 2;
        float4 a = make_float4(0.f, 0.f, 0.f, 0.f);
        if (row0 + r < N_NODES) a = *(const float4*)&A[(size_t)(row0 + r) * 128 + k4];
        *(float4*)&As[r][k4] = a;
    }
    for (int i = 0; i < 8; ++i) {
        int idx = t + i * 256;
        int k = idx >> 4, c4 = (idx & 15) << 2;
        *(float4*)&Bs[k][c4] = *(const float4*)&W[k * 128 + cb + c4];
    }
    __syncthreads();

    int tx = t & 15, ty = t >> 4;
    int rb = ty * 4, cc = tx * 4;
    float acc[4][4] = {};
    for (int k = 0; k < 128; ++k) {
        float a0 = As[rb + 0][k];
        float a1 = As[rb + 1][k];
        float a2 = As[rb + 2][k];
        float a3 = As[rb + 3][k];
        float4 b = *(float4*)&Bs[k][cc];
        acc[0][0] += a0 * b.x; acc[0][1] += a0 * b.y; acc[0][2] += a0 * b.z; acc[0][3] += a0 * b.w;
        acc[1][0] += a1 * b.x; acc[1][1] += a1 * b.y; acc[1][2] += a1 * b.z; acc[1][3] += a1 * b.w;
        acc[2][0] += a2 * b.x; acc[2][1] += a2 * b.y; acc[2][2] += a2 * b.z; acc[2][3] += a2 * b.w;
        acc[3][0] += a3 * b.x; acc[3][1] += a3 * b.y; acc[3][2] += a3 * b.z; acc[3][3] += a3 * b.w;
    }
    float4 bb = *(const float4*)&bias[cb + cc];
    for (int i = 0; i < 4; ++i) {
        int row = row0 + rb + i;
        if (row < N_NODES) {
            float4 o;
            o.x = acc[i][0] + bb.x; o.y = acc[i][1] + bb.y;
            o.z = acc[i][2] + bb.z; o.w = acc[i][3] + bb.w;
            *(float4*)&out[(size_t)row * 256 + by * 64 + cc] = o;
        }
    }
}

// ---------------------------------------------------------------- attention logits (CSR form)
// One wave per dst node; Q[n] in regs; 4x-unrolled K[src] gathers.
__global__ __launch_bounds__(256) void alpha_csr_kernel(
    const float* __restrict__ buf,           // Q (cols 0-127) | K (cols 128-255)
    const int* __restrict__ srcs, const int* __restrict__ rowptr,
    float* __restrict__ ex, float* __restrict__ denom) {
    int n = (blockIdx.x * 256 + threadIdx.x) >> 6;
    int lane = threadIdx.x & 63;
    if (n >= N_NODES) return;
    int hd = lane >> 4;
    float2 q2 = *(const float2*)&buf[(size_t)n * 256 + 2 * lane];
    int e0 = rowptr[n], e1 = rowptr[n + 1];
    float dsum = 0.f;
    const float sc = 0.17677669529663687f;   // 1/sqrt(32)
    int idx = e0;
    for (; idx + 3 < e1; idx += 4) {
        int s0 = srcs[idx], s1 = srcs[idx + 1], s2 = srcs[idx + 2], s3 = srcs[idx + 3];
        float2 k0 = *(const float2*)&buf[(size_t)s0 * 256 + 128 + 2 * lane];
        float2 k1 = *(const float2*)&buf[(size_t)s1 * 256 + 128 + 2 * lane];
        float2 k2 = *(const float2*)&buf[(size_t)s2 * 256 + 128 + 2 * lane];
        float2 k3 = *(const float2*)&buf[(size_t)s3 * 256 + 128 + 2 * lane];
        float p0 = q2.x * k0.x + q2.y * k0.y;
        float p1 = q2.x * k1.x + q2.y * k1.y;
        float p2 = q2.x * k2.x + q2.y * k2.y;
        float p3 = q2.x * k3.x + q2.y * k3.y;
        p0 += __shfl_xor(p0, 1); p1 += __shfl_xor(p1, 1); p2 += __shfl_xor(p2, 1); p3 += __shfl_xor(p3, 1);
        p0 += __shfl_xor(p0, 2); p1 += __shfl_xor(p1, 2); p2 += __shfl_xor(p2, 2); p3 += __shfl_xor(p3, 2);
        p0 += __shfl_xor(p0, 4); p1 += __shfl_xor(p1, 4); p2 += __shfl_xor(p2, 4); p3 += __shfl_xor(p3, 4);
        p0 += __shfl_xor(p0, 8); p1 += __shfl_xor(p1, 8); p2 += __shfl_xor(p2, 8); p3 += __shfl_xor(p3, 8);
        float e0v = expf(p0 * sc), e1v = expf(p1 * sc);
        float e2v = expf(p2 * sc), e3v = expf(p3 * sc);
        if ((lane & 15) == 0) {
            ex[(size_t)idx * 4 + hd]       = e0v;
            ex[(size_t)(idx + 1) * 4 + hd] = e1v;
            ex[(size_t)(idx + 2) * 4 + hd] = e2v;
            ex[(size_t)(idx + 3) * 4 + hd] = e3v;
            dsum += (e0v + e1v) + (e2v + e3v);
        }
    }
    for (; idx < e1; ++idx) {
        int s0 = srcs[idx];
        float2 k0 = *(const float2*)&buf[(size_t)s0 * 256 + 128 + 2 * lane];
        float p0 = q2.x * k0.x + q2.y * k0.y;
        p0 += __shfl_xor(p0, 1);
        p0 += __shfl_xor(p0, 2);
        p0 += __shfl_xor(p0, 4);
        p0 += __shfl_xor(p0, 8);
        float e0v = expf(p0 * sc);
        if ((lane & 15) == 0) {
            ex[(size_t)idx * 4 + hd] = e0v;
            dsum += e0v;
        }
    }
    if ((lane & 15) == 0) denom[n * 4 + hd] = dsum;
}

// ---------------------------------------------------------------- aggregate + skip + LN + ReLU
// One wave per node; lane owns channels (2*lane, 2*lane+1); head = lane>>4.
// buf holds V (cols 0-127) | S=skip (cols 128-255).  4x-unrolled gathers.
__global__ __launch_bounds__(256) void agg_ln_kernel(
    const float* __restrict__ buf, const int* __restrict__ srcs,
    const int* __restrict__ rowptr,
    const float* __restrict__ ex, const float* __restrict__ denom,
    const float* __restrict__ gamma, const float* __restrict__ beta,
    float* __restrict__ hout) {
    int n = (blockIdx.x * 256 + threadIdx.x) >> 6;
    int lane = threadIdx.x & 63;
    if (n >= N_NODES) return;
    int hd = lane >> 4;
    float dinv = 1.0f / (denom[n * 4 + hd] + 1e-16f);
    int e0 = rowptr[n], e1 = rowptr[n + 1];
    float accx = 0.f, accy = 0.f;
    int idx = e0;
    for (; idx + 3 < e1; idx += 4) {
        int s0 = srcs[idx], s1 = srcs[idx + 1], s2 = srcs[idx + 2], s3 = srcs[idx + 3];
        float w0 = ex[(size_t)idx * 4 + hd];
        float w1 = ex[(size_t)(idx + 1) * 4 + hd];
        float w2 = ex[(size_t)(idx + 2) * 4 + hd];
        float w3 = ex[(size_t)(idx + 3) * 4 + hd];
        float2 v0 = *(const float2*)&buf[(size_t)s0 * 256 + 2 * lane];
        float2 v1 = *(const float2*)&buf[(size_t)s1 * 256 + 2 * lane];
        float2 v2 = *(const float2*)&buf[(size_t)s2 * 256 + 2 * lane];
        float2 v3 = *(const float2*)&buf[(size_t)s3 * 256 + 2 * lane];
        accx += v0.x * w0 + v1.x * w1 + v2.x * w2 + v3.x * w3;
        accy += v0.y * w0 + v1.y * w1 + v2.y * w2 + v3.y * w3;
    }
    for (; idx < e1; ++idx) {
        int s0 = srcs[idx];
        float w0 = ex[(size_t)idx * 4 + hd];
        float2 v0 = *(const float2*)&buf[(size_t)s0 * 256 + 2 * lane];
        accx += v0.x * w0;
        accy += v0.y * w0;
    }
    accx *= dinv;
    accy *= dinv;
    float2 sk = *(const float2*)&buf[(size_t)n * 256 + 128 + 2 * lane];
    float vx = accx + sk.x, vy = accy + sk.y;
    float sum = vx + vy;
    for (int msk = 1; msk < 64; msk <<= 1) sum += __shfl_xor(sum, msk);
    float mu = sum * (1.0f / 128.0f);
    float dx = vx - mu, dy = vy - mu;
    float sq = dx * dx + dy * dy;
    for (int msk = 1; msk < 64; msk <<= 1) sq += __shfl_xor(sq, msk);
    float rs = rsqrtf(sq * (1.0f / 128.0f) + 1e-5f);
    int c = 2 * lane;
    float o0 = dx * rs * gamma[c]     + beta[c];
    float o1 = dy * rs * gamma[c + 1] + beta[c + 1];
    o0 = fmaxf(o0, 0.f);
    o1 = fmaxf(o1, 0.f);
    *(float2*)&hout[(size_t)n * 128 + c] = make_float2(o0, o1);
}

// ---------------------------------------------------------------- classifier
__global__ __launch_bounds__(256) void out_gemm_kernel(
    const float* __restrict__ h, const float* __restrict__ Wout,
    const float* __restrict__ bout, float* __restrict__ out) {
    __shared__ float hs[32][132];
    __shared__ float ws[128 * NCLS_];
    __shared__ float bsd[NCLS_];
    int t = threadIdx.x;
    int n0 = blockIdx.x * 32;
    for (int i = t; i < 128 * NCLS_; i += 256) ws[i] = Wout[i];
    if (t < NCLS_) bsd[t] = bout[t];
    for (int i = t; i < 1024; i += 256) {
        int r = i >> 5, k4 = (i & 31) << 2;
        float4 a = make_float4(0.f, 0.f, 0.f, 0.f);
        if (n0 + r < N_NODES) a = *(const float4*)&h[(size_t)(n0 + r) * 128 + k4];
        *(float4*)&hs[r][k4] = a;
    }
    __syncthreads();
    int r = t >> 3, j0 = (t & 7) * 5;
    float acc[5];
    for (int j = 0; j < 5; ++j) acc[j] = bsd[j0 + j];
    for (int k = 0; k < 128; ++k) {
        float a = hs[r][k];
        for (int j = 0; j < 5; ++j) acc[j] += a * ws[k * NCLS_ + j0 + j];
    }
    int n = n0 + r;
    if (n < N_NODES) {
        for (int j = 0; j < 5; ++j) out[(size_t)n * NCLS_ + j0 + j] = acc[j];
    }
}

// ---------------------------------------------------------------- launch
extern "C" void kernel_launch(void* const* d_in, const int* in_sizes, int n_in,
                              void* d_out, int out_size, void* d_ws, size_t ws_size,
                              hipStream_t stream) {
    const float* x    = (const float*)d_in[0];
    const int*   ei   = (const int*)d_in[1];
    const int*   src  = ei;
    const int*   dst  = ei + N_EDGES;
    const float* Wq   = (const float*)d_in[2];
    const float* bq   = (const float*)d_in[3];
    const float* Wk   = (const float*)d_in[4];
    const float* bk   = (const float*)d_in[5];
    const float* Wv   = (const float*)d_in[6];
    const float* bv   = (const float*)d_in[7];
    const float* Wsk  = (const float*)d_in[8];
    const float* bsk  = (const float*)d_in[9];
    const float* gmm  = (const float*)d_in[10];
    const float* bta  = (const float*)d_in[11];
    const float* Wout = (const float*)d_in[12];
    const float* bout = (const float*)d_in[13];
    float* outp = (float*)d_out;

    char* p = (char*)d_ws;
    auto carve = [&](size_t bytes) {
        char* r = p;
        p += (bytes + 255) & ~(size_t)255;
        return r;
    };
    float* buf   = (float*)carve((size_t)N_NODES * 256 * 4);  // Q|K then V|S
    float* h     = (float*)carve((size_t)N_NODES * 128 * 4);  // layer out (reused)
    float* exb   = (float*)carve((size_t)N_EDGES * 4 * 4);    // CSR-ordered ex
    float* denom = (float*)carve((size_t)N_NODES * 4 * 4);
    int* deg     = (int*)carve((size_t)N_NODES * 4);
    int* rowptr  = (int*)carve((size_t)(N_NODES + 1) * 4);
    int* cursor  = (int*)carve((size_t)N_NODES * 4);
    int* srcs    = (int*)carve((size_t)N_EDGES * 4);          // CSR-ordered src ids
    int* sums    = (int*)carve((size_t)NSCAN_BLOCKS * 4);

    // CSR by dst (reused by both layers) — hierarchical scan + XCD-local scatter
    zero_i32_kernel<<<(N_NODES + 255) / 256, 256, 0, stream>>>(deg, N_NODES);
    hist_kernel<<<2048, 256, 0, stream>>>(dst, deg);
    scan_block_kernel<<<NSCAN_BLOCKS, 1024, 0, stream>>>(deg, rowptr, sums);
    scan_sums_kernel<<<1, 128, 0, stream>>>(sums);
    scan_add_kernel<<<(N_NODES + 255) / 256, 256, 0, stream>>>(rowptr, sums, cursor);
    scatter_kernel<<<2048, 256, 0, stream>>>(src, dst, cursor, srcs);

    for (int l = 0; l < 2; ++l) {
        const float* hin = l ? (const float*)h : x;
        dim3 g((N_NODES + 63) / 64, 4);
        // Q|K
        gemm_pair_kernel<<<g, 256, 0, stream>>>(
            hin, Wq + l * 16384, Wk + l * 16384, bq + l * 128, bk + l * 128, buf);
        alpha_csr_kernel<<<(N_NODES + 3) / 4, 256, 0, stream>>>(buf, srcs, rowptr, exb, denom);
        // V|S overwrite buf (Q/K dead once exb+denom exist)
        gemm_pair_kernel<<<g, 256, 0, stream>>>(
            hin, Wv + l * 16384, Wsk + l * 16384, bv + l * 128, bsk + l * 128, buf);
        agg_ln_kernel<<<(N_NODES + 3) / 4, 256, 0, stream>>>(
            buf, srcs, rowptr, exb, denom, gmm + l * 128, bta + l * 128, h);
    }
    out_gemm_kernel<<<(N_NODES + 31) / 32, 256, 0, stream>>>(h, Wout, bout, outp);
}

// Round 6
// 896.217 us; speedup vs baseline: 2.3070x; 1.3728x over previous
//
#include <hip/hip_runtime.h>
#include <math.h>

#define N_NODES 100000
#define N_EDGES 1600000
#define NCLS_ 40
#define NSCAN_BLOCKS ((N_NODES + 1023) / 1024)   // 98
#define DRANGE 12500                              // N_NODES / 8 XCD groups

typedef short bf16x8 __attribute__((ext_vector_type(8)));
typedef float f32x4 __attribute__((ext_vector_type(4)));

// bf16 helpers (RNE pack, exact unpack)
__device__ __forceinline__ unsigned short f2b(float f) {
    union { float f; unsigned u; } v; v.f = f;
    unsigned r = v.u + 0x7fffu + ((v.u >> 16) & 1u);
    return (unsigned short)(r >> 16);
}
__device__ __forceinline__ float2 up2(unsigned u) {   // packed pair -> floats
    union { unsigned u; float f; } a, b;
    a.u = u << 16; b.u = u & 0xffff0000u;
    return make_float2(a.f, b.f);
}
__device__ __forceinline__ unsigned pk2(float x, float y) {
    return (unsigned)f2b(x) | ((unsigned)f2b(y) << 16);
}
__device__ __forceinline__ float b2f(unsigned short s) {
    union { unsigned u; float f; } v; v.u = ((unsigned)s) << 16;
    return v.f;
}

// ---------------------------------------------------------------- utils
__global__ void zero_i32_kernel(int* __restrict__ p, int n) {
    int i = blockIdx.x * blockDim.x + threadIdx.x;
    if (i < n) p[i] = 0;
}

// ---------------------------------------------------------------- CSR build
// XCD-localized histogram (R4->R5 win: write-combining in per-XCD L2)
__global__ __launch_bounds__(256) void hist_kernel(
    const int* __restrict__ dst, int* __restrict__ deg) {
    int group = blockIdx.x & 7;
    int gblk  = blockIdx.x >> 3;
    int nblk  = gridDim.x >> 3;
    int lo = group * DRANGE, hi = lo + DRANGE;
    for (int i = gblk * 256 + threadIdx.x; i < N_EDGES; i += nblk * 256) {
        int d = dst[i];
        if (d >= lo && d < hi) atomicAdd(&deg[d], 1);
    }
}

__global__ __launch_bounds__(1024) void scan_block_kernel(
    const int* __restrict__ deg, int* __restrict__ rowptr, int* __restrict__ sums) {
    __shared__ int tmp[1024];
    int t = threadIdx.x;
    int i = blockIdx.x * 1024 + t;
    int v = (i < N_NODES) ? deg[i] : 0;
    tmp[t] = v;
    __syncthreads();
    for (int d = 1; d < 1024; d <<= 1) {
        int add = (t >= d) ? tmp[t - d] : 0;
        __syncthreads();
        tmp[t] += add;
        __syncthreads();
    }
    if (i < N_NODES) rowptr[i] = tmp[t] - v;
    if (t == 1023) sums[blockIdx.x] = tmp[1023];
}

__global__ __launch_bounds__(128) void scan_sums_kernel(int* __restrict__ sums) {
    __shared__ int tmp[128];
    int t = threadIdx.x;
    int v = (t < NSCAN_BLOCKS) ? sums[t] : 0;
    tmp[t] = v;
    __syncthreads();
    for (int d = 1; d < 128; d <<= 1) {
        int add = (t >= d) ? tmp[t - d] : 0;
        __syncthreads();
        tmp[t] += add;
        __syncthreads();
    }
    if (t < NSCAN_BLOCKS) sums[t] = tmp[t] - v;
}

__global__ void scan_add_kernel(int* __restrict__ rowptr, const int* __restrict__ sums,
                                int* __restrict__ cursor) {
    int i = blockIdx.x * blockDim.x + threadIdx.x;
    if (i < N_NODES) {
        int val = rowptr[i] + sums[i >> 10];
        rowptr[i] = val;
        cursor[i] = val;
    }
    if (i == 0) rowptr[N_NODES] = N_EDGES;
}

__global__ __launch_bounds__(256) void scatter_kernel(
    const int* __restrict__ src, const int* __restrict__ dst,
    int* __restrict__ cursor, int* __restrict__ srcs) {
    int group = blockIdx.x & 7;
    int gblk  = blockIdx.x >> 3;
    int nblk  = gridDim.x >> 3;
    int lo = group * DRANGE, hi = lo + DRANGE;
    for (int i = gblk * 256 + threadIdx.x; i < N_EDGES; i += nblk * 256) {
        int d = dst[i];
        if (d >= lo && d < hi) {
            int pos = atomicAdd(&cursor[d], 1);
            srcs[pos] = src[i];
        }
    }
}

// ---------------------------------------------------------------- QKVS GEMM (bf16 MFMA)
// qkvs[N,512](bf16) = A[N,128] @ [Wq|Wk|Wv|Ws] + bias.  64x64 tile, 4 waves,
// mfma_f32_16x16x32_bf16. Layouts (verified m89/m91): A[m=lane&15][k=quad*8+j],
// B[k=quad*8+j][n=lane&15], D[row=quad*4+reg][col=lane&15].
// LDS rows padded +8 shorts: row stride 272B -> 2-way bank alias only (free).
__global__ __launch_bounds__(256) void gemm_qkvs_kernel(
    const void* __restrict__ Ap, int a_is_bf16,
    const float* __restrict__ W0, const float* __restrict__ W1,
    const float* __restrict__ W2, const float* __restrict__ W3,
    const float* __restrict__ b0, const float* __restrict__ b1,
    const float* __restrict__ b2, const float* __restrict__ b3,
    unsigned short* __restrict__ out) {
    __shared__ unsigned short As[64][136];
    __shared__ unsigned short Bs[64][136];
    int t = threadIdx.x;
    int row0 = blockIdx.x * 64;
    int by = blockIdx.y;                      // [0,8): mat = by>>1, col-half = by&1
    int mat = by >> 1;
    const float* W    = (mat == 0) ? W0 : (mat == 1) ? W1 : (mat == 2) ? W2 : W3;
    const float* bias = (mat == 0) ? b0 : (mat == 1) ? b1 : (mat == 2) ? b2 : b3;
    int cb = (by & 1) * 64;

    // stage A (convert fp32->bf16 or copy bf16)
    if (a_is_bf16) {
        const unsigned short* A = (const unsigned short*)Ap;
        for (int i = 0; i < 8; ++i) {
            int idx = t + i * 256;
            int r = idx >> 5, k4 = (idx & 31) << 2;
            ushort4 v = make_ushort4(0, 0, 0, 0);
            if (row0 + r < N_NODES) v = *(const ushort4*)&A[(size_t)(row0 + r) * 128 + k4];
            *(ushort4*)&As[r][k4] = v;
        }
    } else {
        const float* A = (const float*)Ap;
        for (int i = 0; i < 8; ++i) {
            int idx = t + i * 256;
            int r = idx >> 5, k4 = (idx & 31) << 2;
            float4 v = make_float4(0.f, 0.f, 0.f, 0.f);
            if (row0 + r < N_NODES) v = *(const float4*)&A[(size_t)(row0 + r) * 128 + k4];
            ushort4 o;
            o.x = f2b(v.x); o.y = f2b(v.y); o.z = f2b(v.z); o.w = f2b(v.w);
            *(ushort4*)&As[r][k4] = o;
        }
    }
    // stage W transposed into Bs[n][k] (coalesced global read, scattered LDS write)
    for (int i = 0; i < 8; ++i) {
        int idx = t + i * 256;
        int k = idx >> 4, c4 = (idx & 15) << 2;
        float4 w = *(const float4*)&W[k * 128 + cb + c4];
        Bs[c4 + 0][k] = f2b(w.x);
        Bs[c4 + 1][k] = f2b(w.y);
        Bs[c4 + 2][k] = f2b(w.z);
        Bs[c4 + 3][k] = f2b(w.w);
    }
    __syncthreads();

    int wv = t >> 6, lane = t & 63;
    int ln = lane & 15, quad = lane >> 4;
    f32x4 acc[4];
    for (int c = 0; c < 4; ++c) acc[c] = (f32x4){0.f, 0.f, 0.f, 0.f};
    for (int ks = 0; ks < 4; ++ks) {
        int k0 = ks * 32 + quad * 8;
        bf16x8 a = *(bf16x8*)&As[wv * 16 + ln][k0];
        for (int c = 0; c < 4; ++c) {
            bf16x8 b = *(bf16x8*)&Bs[c * 16 + ln][k0];
            acc[c] = __builtin_amdgcn_mfma_f32_16x16x32_bf16(a, b, acc[c], 0, 0, 0);
        }
    }
    int gcol0 = by * 64;
    for (int c = 0; c < 4; ++c) {
        float bb = bias[(by & 1) * 64 + c * 16 + ln];
        for (int r = 0; r < 4; ++r) {
            int row = row0 + wv * 16 + quad * 4 + r;
            if (row < N_NODES)
                out[(size_t)row * 512 + gcol0 + c * 16 + ln] = f2b(acc[c][r] + bb);
        }
    }
}

// ---------------------------------------------------------------- attention logits (CSR form)
// qkvs bf16 [N][512]: Q 0-127 | K 128-255 | V 256-383 | S 384-511.
__global__ __launch_bounds__(256) void alpha_csr_kernel(
    const unsigned short* __restrict__ qkvs,
    const int* __restrict__ srcs, const int* __restrict__ rowptr,
    float* __restrict__ ex, float* __restrict__ denom) {
    int n = (blockIdx.x * 256 + threadIdx.x) >> 6;
    int lane = threadIdx.x & 63;
    if (n >= N_NODES) return;
    int hd = lane >> 4;
    float2 q2 = up2(*(const unsigned*)&qkvs[(size_t)n * 512 + 2 * lane]);
    int e0 = rowptr[n], e1 = rowptr[n + 1];
    float dsum = 0.f;
    const float sc = 0.17677669529663687f;   // 1/sqrt(32)
    int idx = e0;
    for (; idx + 3 < e1; idx += 4) {
        int s0 = srcs[idx], s1 = srcs[idx + 1], s2 = srcs[idx + 2], s3 = srcs[idx + 3];
        float2 k0 = up2(*(const unsigned*)&qkvs[(size_t)s0 * 512 + 128 + 2 * lane]);
        float2 k1 = up2(*(const unsigned*)&qkvs[(size_t)s1 * 512 + 128 + 2 * lane]);
        float2 k2 = up2(*(const unsigned*)&qkvs[(size_t)s2 * 512 + 128 + 2 * lane]);
        float2 k3 = up2(*(const unsigned*)&qkvs[(size_t)s3 * 512 + 128 + 2 * lane]);
        float p0 = q2.x * k0.x + q2.y * k0.y;
        float p1 = q2.x * k1.x + q2.y * k1.y;
        float p2 = q2.x * k2.x + q2.y * k2.y;
        float p3 = q2.x * k3.x + q2.y * k3.y;
        p0 += __shfl_xor(p0, 1); p1 += __shfl_xor(p1, 1); p2 += __shfl_xor(p2, 1); p3 += __shfl_xor(p3, 1);
        p0 += __shfl_xor(p0, 2); p1 += __shfl_xor(p1, 2); p2 += __shfl_xor(p2, 2); p3 += __shfl_xor(p3, 2);
        p0 += __shfl_xor(p0, 4); p1 += __shfl_xor(p1, 4); p2 += __shfl_xor(p2, 4); p3 += __shfl_xor(p3, 4);
        p0 += __shfl_xor(p0, 8); p1 += __shfl_xor(p1, 8); p2 += __shfl_xor(p2, 8); p3 += __shfl_xor(p3, 8);
        float e0v = expf(p0 * sc), e1v = expf(p1 * sc);
        float e2v = expf(p2 * sc), e3v = expf(p3 * sc);
        if ((lane & 15) == 0) {
            ex[(size_t)idx * 4 + hd]       = e0v;
            ex[(size_t)(idx + 1) * 4 + hd] = e1v;
            ex[(size_t)(idx + 2) * 4 + hd] = e2v;
            ex[(size_t)(idx + 3) * 4 + hd] = e3v;
            dsum += (e0v + e1v) + (e2v + e3v);
        }
    }
    for (; idx < e1; ++idx) {
        int s0 = srcs[idx];
        float2 k0 = up2(*(const unsigned*)&qkvs[(size_t)s0 * 512 + 128 + 2 * lane]);
        float p0 = q2.x * k0.x + q2.y * k0.y;
        p0 += __shfl_xor(p0, 1);
        p0 += __shfl_xor(p0, 2);
        p0 += __shfl_xor(p0, 4);
        p0 += __shfl_xor(p0, 8);
        float e0v = expf(p0 * sc);
        if ((lane & 15) == 0) {
            ex[(size_t)idx * 4 + hd] = e0v;
            dsum += e0v;
        }
    }
    if ((lane & 15) == 0) denom[n * 4 + hd] = dsum;
}

// ---------------------------------------------------------------- aggregate + skip + LN + ReLU
__global__ __launch_bounds__(256) void agg_ln_kernel(
    const unsigned short* __restrict__ qkvs, const int* __restrict__ srcs,
    const int* __restrict__ rowptr,
    const float* __restrict__ ex, const float* __restrict__ denom,
    const float* __restrict__ gamma, const float* __restrict__ beta,
    unsigned short* __restrict__ hout) {
    int n = (blockIdx.x * 256 + threadIdx.x) >> 6;
    int lane = threadIdx.x & 63;
    if (n >= N_NODES) return;
    int hd = lane >> 4;
    float dinv = 1.0f / (denom[n * 4 + hd] + 1e-16f);
    int e0 = rowptr[n], e1 = rowptr[n + 1];
    float accx = 0.f, accy = 0.f;
    int idx = e0;
    for (; idx + 3 < e1; idx += 4) {
        int s0 = srcs[idx], s1 = srcs[idx + 1], s2 = srcs[idx + 2], s3 = srcs[idx + 3];
        float w0 = ex[(size_t)idx * 4 + hd];
        float w1 = ex[(size_t)(idx + 1) * 4 + hd];
        float w2 = ex[(size_t)(idx + 2) * 4 + hd];
        float w3 = ex[(size_t)(idx + 3) * 4 + hd];
        float2 v0 = up2(*(const unsigned*)&qkvs[(size_t)s0 * 512 + 256 + 2 * lane]);
        float2 v1 = up2(*(const unsigned*)&qkvs[(size_t)s1 * 512 + 256 + 2 * lane]);
        float2 v2 = up2(*(const unsigned*)&qkvs[(size_t)s2 * 512 + 256 + 2 * lane]);
        float2 v3 = up2(*(const unsigned*)&qkvs[(size_t)s3 * 512 + 256 + 2 * lane]);
        accx += v0.x * w0 + v1.x * w1 + v2.x * w2 + v3.x * w3;
        accy += v0.y * w0 + v1.y * w1 + v2.y * w2 + v3.y * w3;
    }
    for (; idx < e1; ++idx) {
        int s0 = srcs[idx];
        float w0 = ex[(size_t)idx * 4 + hd];
        float2 v0 = up2(*(const unsigned*)&qkvs[(size_t)s0 * 512 + 256 + 2 * lane]);
        accx += v0.x * w0;
        accy += v0.y * w0;
    }
    accx *= dinv;
    accy *= dinv;
    float2 sk = up2(*(const unsigned*)&qkvs[(size_t)n * 512 + 384 + 2 * lane]);
    float vx = accx + sk.x, vy = accy + sk.y;
    float sum = vx + vy;
    for (int msk = 1; msk < 64; msk <<= 1) sum += __shfl_xor(sum, msk);
    float mu = sum * (1.0f / 128.0f);
    float dx = vx - mu, dy = vy - mu;
    float sq = dx * dx + dy * dy;
    for (int msk = 1; msk < 64; msk <<= 1) sq += __shfl_xor(sq, msk);
    float rs = rsqrtf(sq * (1.0f / 128.0f) + 1e-5f);
    int c = 2 * lane;
    float o0 = dx * rs * gamma[c]     + beta[c];
    float o1 = dy * rs * gamma[c + 1] + beta[c + 1];
    o0 = fmaxf(o0, 0.f);
    o1 = fmaxf(o1, 0.f);
    *(unsigned*)&hout[(size_t)n * 128 + c] = pk2(o0, o1);
}

// ---------------------------------------------------------------- classifier (h is bf16)
__global__ __launch_bounds__(256) void out_gemm_kernel(
    const unsigned short* __restrict__ h, const float* __restrict__ Wout,
    const float* __restrict__ bout, float* __restrict__ out) {
    __shared__ float hs[32][132];
    __shared__ float ws[128 * NCLS_];
    __shared__ float bsd[NCLS_];
    int t = threadIdx.x;
    int n0 = blockIdx.x * 32;
    for (int i = t; i < 128 * NCLS_; i += 256) ws[i] = Wout[i];
    if (t < NCLS_) bsd[t] = bout[t];
    for (int i = t; i < 1024; i += 256) {
        int r = i >> 5, k4 = (i & 31) << 2;
        float4 a = make_float4(0.f, 0.f, 0.f, 0.f);
        if (n0 + r < N_NODES) {
            ushort4 u = *(const ushort4*)&h[(size_t)(n0 + r) * 128 + k4];
            a = make_float4(b2f(u.x), b2f(u.y), b2f(u.z), b2f(u.w));
        }
        *(float4*)&hs[r][k4] = a;
    }
    __syncthreads();
    int r = t >> 3, j0 = (t & 7) * 5;
    float acc[5];
    for (int j = 0; j < 5; ++j) acc[j] = bsd[j0 + j];
    for (int k = 0; k < 128; ++k) {
        float a = hs[r][k];
        for (int j = 0; j < 5; ++j) acc[j] += a * ws[k * NCLS_ + j0 + j];
    }
    int n = n0 + r;
    if (n < N_NODES) {
        for (int j = 0; j < 5; ++j) out[(size_t)n * NCLS_ + j0 + j] = acc[j];
    }
}

// ---------------------------------------------------------------- launch
extern "C" void kernel_launch(void* const* d_in, const int* in_sizes, int n_in,
                              void* d_out, int out_size, void* d_ws, size_t ws_size,
                              hipStream_t stream) {
    const float* x    = (const float*)d_in[0];
    const int*   ei   = (const int*)d_in[1];
    const int*   src  = ei;
    const int*   dst  = ei + N_EDGES;
    const float* Wq   = (const float*)d_in[2];
    const float* bq   = (const float*)d_in[3];
    const float* Wk   = (const float*)d_in[4];
    const float* bk   = (const float*)d_in[5];
    const float* Wv   = (const float*)d_in[6];
    const float* bv   = (const float*)d_in[7];
    const float* Wsk  = (const float*)d_in[8];
    const float* bsk  = (const float*)d_in[9];
    const float* gmm  = (const float*)d_in[10];
    const float* bta  = (const float*)d_in[11];
    const float* Wout = (const float*)d_in[12];
    const float* bout = (const float*)d_in[13];
    float* outp = (float*)d_out;

    char* p = (char*)d_ws;
    auto carve = [&](size_t bytes) {
        char* r = p;
        p += (bytes + 255) & ~(size_t)255;
        return r;
    };
    // ~163 MB total
    unsigned short* qkvs = (unsigned short*)carve((size_t)N_NODES * 512 * 2); // bf16 Q|K|V|S
    unsigned short* h    = (unsigned short*)carve((size_t)N_NODES * 128 * 2); // bf16 layer out
    float* exb   = (float*)carve((size_t)N_EDGES * 4 * 4);
    float* denom = (float*)carve((size_t)N_NODES * 4 * 4);
    int* deg     = (int*)carve((size_t)N_NODES * 4);
    int* rowptr  = (int*)carve((size_t)(N_NODES + 1) * 4);
    int* cursor  = (int*)carve((size_t)N_NODES * 4);
    int* srcs    = (int*)carve((size_t)N_EDGES * 4);
    int* sums    = (int*)carve((size_t)NSCAN_BLOCKS * 4);

    // CSR by dst (reused by both layers)
    zero_i32_kernel<<<(N_NODES + 255) / 256, 256, 0, stream>>>(deg, N_NODES);
    hist_kernel<<<2048, 256, 0, stream>>>(dst, deg);
    scan_block_kernel<<<NSCAN_BLOCKS, 1024, 0, stream>>>(deg, rowptr, sums);
    scan_sums_kernel<<<1, 128, 0, stream>>>(sums);
    scan_add_kernel<<<(N_NODES + 255) / 256, 256, 0, stream>>>(rowptr, sums, cursor);
    scatter_kernel<<<2048, 256, 0, stream>>>(src, dst, cursor, srcs);

    for (int l = 0; l < 2; ++l) {
        const void* hin = l ? (const void*)h : (const void*)x;
        dim3 g((N_NODES + 63) / 64, 8);
        gemm_qkvs_kernel<<<g, 256, 0, stream>>>(
            hin, l, Wq + l * 16384, Wk + l * 16384, Wv + l * 16384, Wsk + l * 16384,
            bq + l * 128, bk + l * 128, bv + l * 128, bsk + l * 128, qkvs);
        alpha_csr_kernel<<<(N_NODES + 3) / 4, 256, 0, stream>>>(qkvs, srcs, rowptr, exb, denom);
        agg_ln_kernel<<<(N_NODES + 3) / 4, 256, 0, stream>>>(
            qkvs, srcs, rowptr, exb, denom, gmm + l * 128, bta + l * 128, h);
    }
    out_gemm_kernel<<<(N_NODES + 31) / 32, 256, 0, stream>>>(h, Wout, bout, outp);
}

// Round 7
// 887.536 us; speedup vs baseline: 2.3296x; 1.0098x over previous
//
#include <hip/hip_runtime.h>
#include <math.h>

#define N_NODES 100000
#define N_EDGES 1600000
#define NCLS_ 40
#define NSCAN_BLOCKS ((N_NODES + 1023) / 1024)   // 98
#define DRANGE 12500                              // N_NODES / 8 XCD groups

typedef short bf16x8 __attribute__((ext_vector_type(8)));
typedef float f32x4 __attribute__((ext_vector_type(4)));

// bf16 helpers (RNE pack, exact unpack)
__device__ __forceinline__ unsigned short f2b(float f) {
    union { float f; unsigned u; } v; v.f = f;
    unsigned r = v.u + 0x7fffu + ((v.u >> 16) & 1u);
    return (unsigned short)(r >> 16);
}
__device__ __forceinline__ float2 up2(unsigned u) {   // packed pair -> floats
    union { unsigned u; float f; } a, b;
    a.u = u << 16; b.u = u & 0xffff0000u;
    return make_float2(a.f, b.f);
}
__device__ __forceinline__ unsigned pk2(float x, float y) {
    return (unsigned)f2b(x) | ((unsigned)f2b(y) << 16);
}
__device__ __forceinline__ float b2f(unsigned short s) {
    union { unsigned u; float f; } v; v.u = ((unsigned)s) << 16;
    return v.f;
}

// ---------------------------------------------------------------- utils
__global__ void zero_i32_kernel(int* __restrict__ p, int n) {
    int i = blockIdx.x * blockDim.x + threadIdx.x;
    if (i < n) p[i] = 0;
}

// ---------------------------------------------------------------- CSR build
// XCD-localized histogram (R4->R5 win: write-combining in per-XCD L2)
__global__ __launch_bounds__(256) void hist_kernel(
    const int* __restrict__ dst, int* __restrict__ deg) {
    int group = blockIdx.x & 7;
    int gblk  = blockIdx.x >> 3;
    int nblk  = gridDim.x >> 3;
    int lo = group * DRANGE, hi = lo + DRANGE;
    for (int i = gblk * 256 + threadIdx.x; i < N_EDGES; i += nblk * 256) {
        int d = dst[i];
        if (d >= lo && d < hi) atomicAdd(&deg[d], 1);
    }
}

__global__ __launch_bounds__(1024) void scan_block_kernel(
    const int* __restrict__ deg, int* __restrict__ rowptr, int* __restrict__ sums) {
    __shared__ int tmp[1024];
    int t = threadIdx.x;
    int i = blockIdx.x * 1024 + t;
    int v = (i < N_NODES) ? deg[i] : 0;
    tmp[t] = v;
    __syncthreads();
    for (int d = 1; d < 1024; d <<= 1) {
        int add = (t >= d) ? tmp[t - d] : 0;
        __syncthreads();
        tmp[t] += add;
        __syncthreads();
    }
    if (i < N_NODES) rowptr[i] = tmp[t] - v;
    if (t == 1023) sums[blockIdx.x] = tmp[1023];
}

__global__ __launch_bounds__(128) void scan_sums_kernel(int* __restrict__ sums) {
    __shared__ int tmp[128];
    int t = threadIdx.x;
    int v = (t < NSCAN_BLOCKS) ? sums[t] : 0;
    tmp[t] = v;
    __syncthreads();
    for (int d = 1; d < 128; d <<= 1) {
        int add = (t >= d) ? tmp[t - d] : 0;
        __syncthreads();
        tmp[t] += add;
        __syncthreads();
    }
    if (t < NSCAN_BLOCKS) sums[t] = tmp[t] - v;
}

__global__ void scan_add_kernel(int* __restrict__ rowptr, const int* __restrict__ sums,
                                int* __restrict__ cursor) {
    int i = blockIdx.x * blockDim.x + threadIdx.x;
    if (i < N_NODES) {
        int val = rowptr[i] + sums[i >> 10];
        rowptr[i] = val;
        cursor[i] = val;
    }
    if (i == 0) rowptr[N_NODES] = N_EDGES;
}

__global__ __launch_bounds__(256) void scatter_kernel(
    const int* __restrict__ src, const int* __restrict__ dst,
    int* __restrict__ cursor, int* __restrict__ srcs) {
    int group = blockIdx.x & 7;
    int gblk  = blockIdx.x >> 3;
    int nblk  = gridDim.x >> 3;
    int lo = group * DRANGE, hi = lo + DRANGE;
    for (int i = gblk * 256 + threadIdx.x; i < N_EDGES; i += nblk * 256) {
        int d = dst[i];
        if (d >= lo && d < hi) {
            int pos = atomicAdd(&cursor[d], 1);
            srcs[pos] = src[i];
        }
    }
}

// ---------------------------------------------------------------- QKVS GEMM (bf16 MFMA)
// qkvs[N,512](bf16) = A[N,128] @ [Wq|Wk|Wv|Ws] + bias.
// ONE block per 64-row tile computes ALL 512 cols: A staged once (R6: the
// by=8 grid re-fetched A 8x -> 201 MB); W (256 KB) is L2-resident across
// blocks. Inner loop over 8 col-groups stages 64x128 of W per iteration.
// LDS rows padded to 138 shorts (69 dwords, gcd(69%32,32)=1): fragment
// b128 reads spread all 32 banks (only free 2-way wave64 alias); B staging
// writes ushort4 at lane-consecutive n -> conflict-free (R6: transpose
// writes were 8-way, 2.6e7 conflict cycles).
__global__ __launch_bounds__(256) void gemm_qkvs_kernel(
    const void* __restrict__ Ap, int a_is_bf16,
    const float* __restrict__ W0, const float* __restrict__ W1,
    const float* __restrict__ W2, const float* __restrict__ W3,
    const float* __restrict__ b0, const float* __restrict__ b1,
    const float* __restrict__ b2, const float* __restrict__ b3,
    unsigned short* __restrict__ out) {
    __shared__ unsigned short As[64][138];
    __shared__ unsigned short Bs[64][138];
    int t = threadIdx.x;
    int row0 = blockIdx.x * 64;

    // stage A (convert fp32->bf16 or copy bf16) — once per block
    if (a_is_bf16) {
        const unsigned short* A = (const unsigned short*)Ap;
        for (int i = 0; i < 8; ++i) {
            int idx = t + i * 256;
            int r = idx >> 5, k4 = (idx & 31) << 2;
            ushort4 v = make_ushort4(0, 0, 0, 0);
            if (row0 + r < N_NODES) v = *(const ushort4*)&A[(size_t)(row0 + r) * 128 + k4];
            *(ushort4*)&As[r][k4] = v;
        }
    } else {
        const float* A = (const float*)Ap;
        for (int i = 0; i < 8; ++i) {
            int idx = t + i * 256;
            int r = idx >> 5, k4 = (idx & 31) << 2;
            float4 v = make_float4(0.f, 0.f, 0.f, 0.f);
            if (row0 + r < N_NODES) v = *(const float4*)&A[(size_t)(row0 + r) * 128 + k4];
            ushort4 o;
            o.x = f2b(v.x); o.y = f2b(v.y); o.z = f2b(v.z); o.w = f2b(v.w);
            *(ushort4*)&As[r][k4] = o;
        }
    }

    int wv = t >> 6, lane = t & 63;
    int ln = lane & 15, quad = lane >> 4;

    for (int g = 0; g < 8; ++g) {
        int mat = g >> 1;
        const float* W    = (mat == 0) ? W0 : (mat == 1) ? W1 : (mat == 2) ? W2 : W3;
        const float* bias = (mat == 0) ? b0 : (mat == 1) ? b1 : (mat == 2) ? b2 : b3;
        int cb = (g & 1) * 64;

        // stage Bs[n][k] for this 64-col group: 64n x 128k bf16.
        // chunk: n = idx&63 (lane-consecutive -> coalesced global, spread LDS),
        // k4 = (idx>>6)*4. W reads: 4 coalesced 256 B row segments.
        for (int i = 0; i < 8; ++i) {
            int idx = t + i * 256;
            int n = idx & 63, k4 = (idx >> 6) << 2;
            ushort4 o;
            o.x = f2b(W[(k4 + 0) * 128 + cb + n]);
            o.y = f2b(W[(k4 + 1) * 128 + cb + n]);
            o.z = f2b(W[(k4 + 2) * 128 + cb + n]);
            o.w = f2b(W[(k4 + 3) * 128 + cb + n]);
            *(ushort4*)&Bs[n][k4] = o;
        }
        __syncthreads();

        f32x4 acc[4];
        for (int c = 0; c < 4; ++c) acc[c] = (f32x4){0.f, 0.f, 0.f, 0.f};
        for (int ks = 0; ks < 4; ++ks) {
            int k0 = ks * 32 + quad * 8;
            bf16x8 a = *(bf16x8*)&As[wv * 16 + ln][k0];
            for (int c = 0; c < 4; ++c) {
                bf16x8 b = *(bf16x8*)&Bs[c * 16 + ln][k0];
                acc[c] = __builtin_amdgcn_mfma_f32_16x16x32_bf16(a, b, acc[c], 0, 0, 0);
            }
        }

        int gcol0 = g * 64;
        for (int c = 0; c < 4; ++c) {
            float bb = bias[cb + c * 16 + ln];
            for (int r = 0; r < 4; ++r) {
                int row = row0 + wv * 16 + quad * 4 + r;
                if (row < N_NODES)
                    out[(size_t)row * 512 + gcol0 + c * 16 + ln] = f2b(acc[c][r] + bb);
            }
        }
        __syncthreads();   // before next group's staging overwrites Bs
    }
}

// ---------------------------------------------------------------- attention logits (CSR form)
// qkvs bf16 [N][512]: Q 0-127 | K 128-255 | V 256-383 | S 384-511.
__global__ __launch_bounds__(256) void alpha_csr_kernel(
    const unsigned short* __restrict__ qkvs,
    const int* __restrict__ srcs, const int* __restrict__ rowptr,
    float* __restrict__ ex, float* __restrict__ denom) {
    int n = (blockIdx.x * 256 + threadIdx.x) >> 6;
    int lane = threadIdx.x & 63;
    if (n >= N_NODES) return;
    int hd = lane >> 4;
    float2 q2 = up2(*(const unsigned*)&qkvs[(size_t)n * 512 + 2 * lane]);
    int e0 = rowptr[n], e1 = rowptr[n + 1];
    float dsum = 0.f;
    const float sc = 0.17677669529663687f;   // 1/sqrt(32)
    int idx = e0;
    for (; idx + 3 < e1; idx += 4) {
        int s0 = srcs[idx], s1 = srcs[idx + 1], s2 = srcs[idx + 2], s3 = srcs[idx + 3];
        float2 k0 = up2(*(const unsigned*)&qkvs[(size_t)s0 * 512 + 128 + 2 * lane]);
        float2 k1 = up2(*(const unsigned*)&qkvs[(size_t)s1 * 512 + 128 + 2 * lane]);
        float2 k2 = up2(*(const unsigned*)&qkvs[(size_t)s2 * 512 + 128 + 2 * lane]);
        float2 k3 = up2(*(const unsigned*)&qkvs[(size_t)s3 * 512 + 128 + 2 * lane]);
        float p0 = q2.x * k0.x + q2.y * k0.y;
        float p1 = q2.x * k1.x + q2.y * k1.y;
        float p2 = q2.x * k2.x + q2.y * k2.y;
        float p3 = q2.x * k3.x + q2.y * k3.y;
        p0 += __shfl_xor(p0, 1); p1 += __shfl_xor(p1, 1); p2 += __shfl_xor(p2, 1); p3 += __shfl_xor(p3, 1);
        p0 += __shfl_xor(p0, 2); p1 += __shfl_xor(p1, 2); p2 += __shfl_xor(p2, 2); p3 += __shfl_xor(p3, 2);
        p0 += __shfl_xor(p0, 4); p1 += __shfl_xor(p1, 4); p2 += __shfl_xor(p2, 4); p3 += __shfl_xor(p3, 4);
        p0 += __shfl_xor(p0, 8); p1 += __shfl_xor(p1, 8); p2 += __shfl_xor(p2, 8); p3 += __shfl_xor(p3, 8);
        float e0v = expf(p0 * sc), e1v = expf(p1 * sc);
        float e2v = expf(p2 * sc), e3v = expf(p3 * sc);
        if ((lane & 15) == 0) {
            ex[(size_t)idx * 4 + hd]       = e0v;
            ex[(size_t)(idx + 1) * 4 + hd] = e1v;
            ex[(size_t)(idx + 2) * 4 + hd] = e2v;
            ex[(size_t)(idx + 3) * 4 + hd] = e3v;
            dsum += (e0v + e1v) + (e2v + e3v);
        }
    }
    for (; idx < e1; ++idx) {
        int s0 = srcs[idx];
        float2 k0 = up2(*(const unsigned*)&qkvs[(size_t)s0 * 512 + 128 + 2 * lane]);
        float p0 = q2.x * k0.x + q2.y * k0.y;
        p0 += __shfl_xor(p0, 1);
        p0 += __shfl_xor(p0, 2);
        p0 += __shfl_xor(p0, 4);
        p0 += __shfl_xor(p0, 8);
        float e0v = expf(p0 * sc);
        if ((lane & 15) == 0) {
            ex[(size_t)idx * 4 + hd] = e0v;
            dsum += e0v;
        }
    }
    if ((lane & 15) == 0) denom[n * 4 + hd] = dsum;
}

// ---------------------------------------------------------------- aggregate + skip + LN + ReLU
__global__ __launch_bounds__(256) void agg_ln_kernel(
    const unsigned short* __restrict__ qkvs, const int* __restrict__ srcs,
    const int* __restrict__ rowptr,
    const float* __restrict__ ex, const float* __restrict__ denom,
    const float* __restrict__ gamma, const float* __restrict__ beta,
    unsigned short* __restrict__ hout) {
    int n = (blockIdx.x * 256 + threadIdx.x) >> 6;
    int lane = threadIdx.x & 63;
    if (n >= N_NODES) return;
    int hd = lane >> 4;
    float dinv = 1.0f / (denom[n * 4 + hd] + 1e-16f);
    int e0 = rowptr[n], e1 = rowptr[n + 1];
    float accx = 0.f, accy = 0.f;
    int idx = e0;
    for (; idx + 3 < e1; idx += 4) {
        int s0 = srcs[idx], s1 = srcs[idx + 1], s2 = srcs[idx + 2], s3 = srcs[idx + 3];
        float w0 = ex[(size_t)idx * 4 + hd];
        float w1 = ex[(size_t)(idx + 1) * 4 + hd];
        float w2 = ex[(size_t)(idx + 2) * 4 + hd];
        float w3 = ex[(size_t)(idx + 3) * 4 + hd];
        float2 v0 = up2(*(const unsigned*)&qkvs[(size_t)s0 * 512 + 256 + 2 * lane]);
        float2 v1 = up2(*(const unsigned*)&qkvs[(size_t)s1 * 512 + 256 + 2 * lane]);
        float2 v2 = up2(*(const unsigned*)&qkvs[(size_t)s2 * 512 + 256 + 2 * lane]);
        float2 v3 = up2(*(const unsigned*)&qkvs[(size_t)s3 * 512 + 256 + 2 * lane]);
        accx += v0.x * w0 + v1.x * w1 + v2.x * w2 + v3.x * w3;
        accy += v0.y * w0 + v1.y * w1 + v2.y * w2 + v3.y * w3;
    }
    for (; idx < e1; ++idx) {
        int s0 = srcs[idx];
        float w0 = ex[(size_t)idx * 4 + hd];
        float2 v0 = up2(*(const unsigned*)&qkvs[(size_t)s0 * 512 + 256 + 2 * lane]);
        accx += v0.x * w0;
        accy += v0.y * w0;
    }
    accx *= dinv;
    accy *= dinv;
    float2 sk = up2(*(const unsigned*)&qkvs[(size_t)n * 512 + 384 + 2 * lane]);
    float vx = accx + sk.x, vy = accy + sk.y;
    float sum = vx + vy;
    for (int msk = 1; msk < 64; msk <<= 1) sum += __shfl_xor(sum, msk);
    float mu = sum * (1.0f / 128.0f);
    float dx = vx - mu, dy = vy - mu;
    float sq = dx * dx + dy * dy;
    for (int msk = 1; msk < 64; msk <<= 1) sq += __shfl_xor(sq, msk);
    float rs = rsqrtf(sq * (1.0f / 128.0f) + 1e-5f);
    int c = 2 * lane;
    float o0 = dx * rs * gamma[c]     + beta[c];
    float o1 = dy * rs * gamma[c + 1] + beta[c + 1];
    o0 = fmaxf(o0, 0.f);
    o1 = fmaxf(o1, 0.f);
    *(unsigned*)&hout[(size_t)n * 128 + c] = pk2(o0, o1);
}

// ---------------------------------------------------------------- classifier (h is bf16)
__global__ __launch_bounds__(256) void out_gemm_kernel(
    const unsigned short* __restrict__ h, const float* __restrict__ Wout,
    const float* __restrict__ bout, float* __restrict__ out) {
    __shared__ float hs[32][132];
    __shared__ float ws[128 * NCLS_];
    __shared__ float bsd[NCLS_];
    int t = threadIdx.x;
    int n0 = blockIdx.x * 32;
    for (int i = t; i < 128 * NCLS_; i += 256) ws[i] = Wout[i];
    if (t < NCLS_) bsd[t] = bout[t];
    for (int i = t; i < 1024; i += 256) {
        int r = i >> 5, k4 = (i & 31) << 2;
        float4 a = make_float4(0.f, 0.f, 0.f, 0.f);
        if (n0 + r < N_NODES) {
            ushort4 u = *(const ushort4*)&h[(size_t)(n0 + r) * 128 + k4];
            a = make_float4(b2f(u.x), b2f(u.y), b2f(u.z), b2f(u.w));
        }
        *(float4*)&hs[r][k4] = a;
    }
    __syncthreads();
    int r = t >> 3, j0 = (t & 7) * 5;
    float acc[5];
    for (int j = 0; j < 5; ++j) acc[j] = bsd[j0 + j];
    for (int k = 0; k < 128; ++k) {
        float a = hs[r][k];
        for (int j = 0; j < 5; ++j) acc[j] += a * ws[k * NCLS_ + j0 + j];
    }
    int n = n0 + r;
    if (n < N_NODES) {
        for (int j = 0; j < 5; ++j) out[(size_t)n * NCLS_ + j0 + j] = acc[j];
    }
}

// ---------------------------------------------------------------- launch
extern "C" void kernel_launch(void* const* d_in, const int* in_sizes, int n_in,
                              void* d_out, int out_size, void* d_ws, size_t ws_size,
                              hipStream_t stream) {
    const float* x    = (const float*)d_in[0];
    const int*   ei   = (const int*)d_in[1];
    const int*   src  = ei;
    const int*   dst  = ei + N_EDGES;
    const float* Wq   = (const float*)d_in[2];
    const float* bq   = (const float*)d_in[3];
    const float* Wk   = (const float*)d_in[4];
    const float* bk   = (const float*)d_in[5];
    const float* Wv   = (const float*)d_in[6];
    const float* bv   = (const float*)d_in[7];
    const float* Wsk  = (const float*)d_in[8];
    const float* bsk  = (const float*)d_in[9];
    const float* gmm  = (const float*)d_in[10];
    const float* bta  = (const float*)d_in[11];
    const float* Wout = (const float*)d_in[12];
    const float* bout = (const float*)d_in[13];
    float* outp = (float*)d_out;

    char* p = (char*)d_ws;
    auto carve = [&](size_t bytes) {
        char* r = p;
        p += (bytes + 255) & ~(size_t)255;
        return r;
    };
    unsigned short* qkvs = (unsigned short*)carve((size_t)N_NODES * 512 * 2); // bf16 Q|K|V|S
    unsigned short* h    = (unsigned short*)carve((size_t)N_NODES * 128 * 2); // bf16 layer out
    float* exb   = (float*)carve((size_t)N_EDGES * 4 * 4);
    float* denom = (float*)carve((size_t)N_NODES * 4 * 4);
    int* deg     = (int*)carve((size_t)N_NODES * 4);
    int* rowptr  = (int*)carve((size_t)(N_NODES + 1) * 4);
    int* cursor  = (int*)carve((size_t)N_NODES * 4);
    int* srcs    = (int*)carve((size_t)N_EDGES * 4);
    int* sums    = (int*)carve((size_t)NSCAN_BLOCKS * 4);

    // CSR by dst (reused by both layers)
    zero_i32_kernel<<<(N_NODES + 255) / 256, 256, 0, stream>>>(deg, N_NODES);
    hist_kernel<<<2048, 256, 0, stream>>>(dst, deg);
    scan_block_kernel<<<NSCAN_BLOCKS, 1024, 0, stream>>>(deg, rowptr, sums);
    scan_sums_kernel<<<1, 128, 0, stream>>>(sums);
    scan_add_kernel<<<(N_NODES + 255) / 256, 256, 0, stream>>>(rowptr, sums, cursor);
    scatter_kernel<<<2048, 256, 0, stream>>>(src, dst, cursor, srcs);

    for (int l = 0; l < 2; ++l) {
        const void* hin = l ? (const void*)h : (const void*)x;
        gemm_qkvs_kernel<<<(N_NODES + 63) / 64, 256, 0, stream>>>(
            hin, l, Wq + l * 16384, Wk + l * 16384, Wv + l * 16384, Wsk + l * 16384,
            bq + l * 128, bk + l * 128, bv + l * 128, bsk + l * 128, qkvs);
        alpha_csr_kernel<<<(N_NODES + 3) / 4, 256, 0, stream>>>(qkvs, srcs, rowptr, exb, denom);
        agg_ln_kernel<<<(N_NODES + 3) / 4, 256, 0, stream>>>(
            qkvs, srcs, rowptr, exb, denom, gmm + l * 128, bta + l * 128, h);
    }
    out_gemm_kernel<<<(N_NODES + 31) / 32, 256, 0, stream>>>(h, Wout, bout, outp);
}

// Round 8
// 716.416 us; speedup vs baseline: 2.8860x; 1.2389x over previous
//
#include <hip/hip_runtime.h>
#include <math.h>

#define N_NODES 100000
#define N_EDGES 1600000
#define NCLS_ 40
#define NSCAN_BLOCKS ((N_NODES + 1023) / 1024)   // 98
#define DRANGE 12500                              // N_NODES / 8 XCD groups

typedef short bf16x8 __attribute__((ext_vector_type(8)));
typedef float f32x4 __attribute__((ext_vector_type(4)));

// bf16 helpers (RNE pack, exact unpack)
__device__ __forceinline__ unsigned short f2b(float f) {
    union { float f; unsigned u; } v; v.f = f;
    unsigned r = v.u + 0x7fffu + ((v.u >> 16) & 1u);
    return (unsigned short)(r >> 16);
}
__device__ __forceinline__ float2 up2(unsigned u) {   // packed pair -> floats
    union { unsigned u; float f; } a, b;
    a.u = u << 16; b.u = u & 0xffff0000u;
    return make_float2(a.f, b.f);
}
__device__ __forceinline__ unsigned pk2(float x, float y) {
    return (unsigned)f2b(x) | ((unsigned)f2b(y) << 16);
}
__device__ __forceinline__ float b2f(unsigned short s) {
    union { unsigned u; float f; } v; v.u = ((unsigned)s) << 16;
    return v.f;
}

// qkvs row layout (512 shorts):
//   [0,128)    Q, channel c at c
//   [128,384)  K/V interleaved: lane l owns shorts 128+4l..128+4l+3 =
//              {K_{2l}, K_{2l+1}, V_{2l}, V_{2l+1}}  -> one 8 B load/edge/lane
//   [384,512)  S (skip), channel c at 384+c

// ---------------------------------------------------------------- utils
__global__ void zero_i32_kernel(int* __restrict__ p, int n) {
    int i = blockIdx.x * blockDim.x + threadIdx.x;
    if (i < n) p[i] = 0;
}

// W preconvert: fp32 [L][128k][128col] -> bf16 B-fragment layout
// Wbf[l][mat][g][n][k], n=col within 64-group, k=0..127.  131072 shorts.
__global__ __launch_bounds__(256) void wconv_kernel(
    const float* __restrict__ Wq, const float* __restrict__ Wk,
    const float* __restrict__ Wv, const float* __restrict__ Ws,
    unsigned short* __restrict__ Wbf) {
    int tid = blockIdx.x * 256 + threadIdx.x;
    if (tid >= 131072) return;
    int k   = tid & 127;
    int n   = (tid >> 7) & 63;
    int g   = (tid >> 13) & 1;
    int mat = (tid >> 14) & 3;
    int l   = tid >> 16;
    const float* W = (mat == 0) ? Wq : (mat == 1) ? Wk : (mat == 2) ? Wv : Ws;
    Wbf[tid] = f2b(W[l * 16384 + k * 128 + g * 64 + n]);
}

// ---------------------------------------------------------------- CSR build
__global__ __launch_bounds__(256) void hist_kernel(
    const int* __restrict__ dst, int* __restrict__ deg) {
    int group = blockIdx.x & 7;
    int gblk  = blockIdx.x >> 3;
    int nblk  = gridDim.x >> 3;
    int lo = group * DRANGE, hi = lo + DRANGE;
    for (int i = gblk * 256 + threadIdx.x; i < N_EDGES; i += nblk * 256) {
        int d = dst[i];
        if (d >= lo && d < hi) atomicAdd(&deg[d], 1);
    }
}

__global__ __launch_bounds__(1024) void scan_block_kernel(
    const int* __restrict__ deg, int* __restrict__ rowptr, int* __restrict__ sums) {
    __shared__ int tmp[1024];
    int t = threadIdx.x;
    int i = blockIdx.x * 1024 + t;
    int v = (i < N_NODES) ? deg[i] : 0;
    tmp[t] = v;
    __syncthreads();
    for (int d = 1; d < 1024; d <<= 1) {
        int add = (t >= d) ? tmp[t - d] : 0;
        __syncthreads();
        tmp[t] += add;
        __syncthreads();
    }
    if (i < N_NODES) rowptr[i] = tmp[t] - v;
    if (t == 1023) sums[blockIdx.x] = tmp[1023];
}

__global__ __launch_bounds__(128) void scan_sums_kernel(int* __restrict__ sums) {
    __shared__ int tmp[128];
    int t = threadIdx.x;
    int v = (t < NSCAN_BLOCKS) ? sums[t] : 0;
    tmp[t] = v;
    __syncthreads();
    for (int d = 1; d < 128; d <<= 1) {
        int add = (t >= d) ? tmp[t - d] : 0;
        __syncthreads();
        tmp[t] += add;
        __syncthreads();
    }
    if (t < NSCAN_BLOCKS) sums[t] = tmp[t] - v;
}

__global__ void scan_add_kernel(int* __restrict__ rowptr, const int* __restrict__ sums,
                                int* __restrict__ cursor) {
    int i = blockIdx.x * blockDim.x + threadIdx.x;
    if (i < N_NODES) {
        int val = rowptr[i] + sums[i >> 10];
        rowptr[i] = val;
        cursor[i] = val;
    }
    if (i == 0) rowptr[N_NODES] = N_EDGES;
}

__global__ __launch_bounds__(256) void scatter_kernel(
    const int* __restrict__ src, const int* __restrict__ dst,
    int* __restrict__ cursor, int* __restrict__ srcs) {
    int group = blockIdx.x & 7;
    int gblk  = blockIdx.x >> 3;
    int nblk  = gridDim.x >> 3;
    int lo = group * DRANGE, hi = lo + DRANGE;
    for (int i = gblk * 256 + threadIdx.x; i < N_EDGES; i += nblk * 256) {
        int d = dst[i];
        if (d >= lo && d < hi) {
            int pos = atomicAdd(&cursor[d], 1);
            srcs[pos] = src[i];
        }
    }
}

// ---------------------------------------------------------------- QKVS GEMM (bf16 MFMA)
// One block per 64-row tile, all 512 cols.  Bs double-buffered with register
// prefetch: group g+1's W loads issue before group g's MFMA (latency hidden),
// ONE barrier per group (R7: 2 barriers/group + exposed load latency left all
// pipes <15% busy).  W pre-converted to bf16 in [n][k] layout -> staging is
// pure ushort4 copies, conflict-free LDS writes.
__global__ __launch_bounds__(256) void gemm_qkvs_kernel(
    const void* __restrict__ Ap, int a_is_bf16,
    const unsigned short* __restrict__ Wbf,   // this layer: [mat][g][64][128]
    const float* __restrict__ b0, const float* __restrict__ b1,
    const float* __restrict__ b2, const float* __restrict__ b3,
    unsigned short* __restrict__ out) {
    __shared__ unsigned short As[64][138];
    __shared__ unsigned short Bs[2][64][138];
    int t = threadIdx.x;
    int row0 = blockIdx.x * 64;

    // stage A once (fp32->bf16 for layer 0, copy for layer 1)
    if (a_is_bf16) {
        const unsigned short* A = (const unsigned short*)Ap;
        for (int i = 0; i < 8; ++i) {
            int idx = t + i * 256;
            int r = idx >> 5, k4 = (idx & 31) << 2;
            ushort4 v = make_ushort4(0, 0, 0, 0);
            if (row0 + r < N_NODES) v = *(const ushort4*)&A[(size_t)(row0 + r) * 128 + k4];
            *(ushort4*)&As[r][k4] = v;
        }
    } else {
        const float* A = (const float*)Ap;
        for (int i = 0; i < 8; ++i) {
            int idx = t + i * 256;
            int r = idx >> 5, k4 = (idx & 31) << 2;
            float4 v = make_float4(0.f, 0.f, 0.f, 0.f);
            if (row0 + r < N_NODES) v = *(const float4*)&A[(size_t)(row0 + r) * 128 + k4];
            ushort4 o;
            o.x = f2b(v.x); o.y = f2b(v.y); o.z = f2b(v.z); o.w = f2b(v.w);
            *(ushort4*)&As[r][k4] = o;
        }
    }

    int wv = t >> 6, lane = t & 63;
    int ln = lane & 15, quad = lane >> 4;

    // prefetch group 0 and stage into Bs[0]
    ushort4 pf[8];
    {
        const unsigned short* Wg = Wbf;           // (mat0,g0)
        for (int i = 0; i < 8; ++i) {
            int idx = t + i * 256;
            pf[i] = *(const ushort4*)&Wg[((idx >> 5) << 7) + ((idx & 31) << 2)];
        }
        for (int i = 0; i < 8; ++i) {
            int idx = t + i * 256;
            *(ushort4*)&Bs[0][idx >> 5][(idx & 31) << 2] = pf[i];
        }
    }
    __syncthreads();

    #pragma unroll
    for (int g = 0; g < 8; ++g) {
        int mat = g >> 1;
        int cur = g & 1;
        const float* bias = (mat == 0) ? b0 : (mat == 1) ? b1 : (mat == 2) ? b2 : b3;
        int cb = (g & 1) * 64;

        // issue next group's W loads (land during MFMA below)
        if (g < 7) {
            const unsigned short* Wg = Wbf + (size_t)(g + 1) * 8192;
            for (int i = 0; i < 8; ++i) {
                int idx = t + i * 256;
                pf[i] = *(const ushort4*)&Wg[((idx >> 5) << 7) + ((idx & 31) << 2)];
            }
        }

        f32x4 acc[4];
        for (int c = 0; c < 4; ++c) acc[c] = (f32x4){0.f, 0.f, 0.f, 0.f};
        for (int ks = 0; ks < 4; ++ks) {
            int k0 = ks * 32 + quad * 8;
            bf16x8 a = *(bf16x8*)&As[wv * 16 + ln][k0];
            for (int c = 0; c < 4; ++c) {
                bf16x8 b = *(bf16x8*)&Bs[cur][c * 16 + ln][k0];
                acc[c] = __builtin_amdgcn_mfma_f32_16x16x32_bf16(a, b, acc[c], 0, 0, 0);
            }
        }

        // epilogue: store through the K/V-interleaved position map
        for (int c = 0; c < 4; ++c) {
            int colInMat = cb + c * 16 + ln;
            float bb = bias[colInMat];
            int pos;
            if (mat == 0)      pos = colInMat;
            else if (mat == 3) pos = 384 + colInMat;
            else               pos = 128 + ((colInMat >> 1) << 2) + ((mat == 2) ? 2 : 0) + (colInMat & 1);
            for (int r = 0; r < 4; ++r) {
                int row = row0 + wv * 16 + quad * 4 + r;
                if (row < N_NODES)
                    out[(size_t)row * 512 + pos] = f2b(acc[c][r] + bb);
            }
        }

        // stage next group into the other half
        if (g < 7) {
            int nxt = cur ^ 1;
            for (int i = 0; i < 8; ++i) {
                int idx = t + i * 256;
                *(ushort4*)&Bs[nxt][idx >> 5][(idx & 31) << 2] = pf[i];
            }
        }
        __syncthreads();
    }
}

// ---------------------------------------------------------------- fused edge pass
// One wave per dst node.  Per edge: ONE 8 B load/lane fetches the lane's K-pair
// AND V-pair (interleaved layout).  Unnormalized accumulate acc += ex*V,
// dsum += ex (softmax is linear without max-shift; alpha~N(0,1), no overflow);
// normalize + skip + LN + ReLU at the end.  No ex/denom buffers.
__global__ __launch_bounds__(256) void edge_fused_kernel(
    const unsigned short* __restrict__ qkvs,
    const int* __restrict__ srcs, const int* __restrict__ rowptr,
    const float* __restrict__ gamma, const float* __restrict__ beta,
    unsigned short* __restrict__ hout) {
    int n = (blockIdx.x * 256 + threadIdx.x) >> 6;
    int lane = threadIdx.x & 63;
    if (n >= N_NODES) return;
    float2 q2 = up2(*(const unsigned*)&qkvs[(size_t)n * 512 + 2 * lane]);
    float2 sk = up2(*(const unsigned*)&qkvs[(size_t)n * 512 + 384 + 2 * lane]);
    int e0 = rowptr[n], e1 = rowptr[n + 1];
    float accx = 0.f, accy = 0.f, dsum = 0.f;
    const float sc = 0.17677669529663687f;   // 1/sqrt(32)
    int idx = e0;
    for (; idx + 3 < e1; idx += 4) {
        int s0 = srcs[idx], s1 = srcs[idx + 1], s2 = srcs[idx + 2], s3 = srcs[idx + 3];
        uint2 kv0 = *(const uint2*)&qkvs[(size_t)s0 * 512 + 128 + 4 * lane];
        uint2 kv1 = *(const uint2*)&qkvs[(size_t)s1 * 512 + 128 + 4 * lane];
        uint2 kv2 = *(const uint2*)&qkvs[(size_t)s2 * 512 + 128 + 4 * lane];
        uint2 kv3 = *(const uint2*)&qkvs[(size_t)s3 * 512 + 128 + 4 * lane];
        float2 k0 = up2(kv0.x), k1 = up2(kv1.x), k2 = up2(kv2.x), k3 = up2(kv3.x);
        float p0 = q2.x * k0.x + q2.y * k0.y;
        float p1 = q2.x * k1.x + q2.y * k1.y;
        float p2 = q2.x * k2.x + q2.y * k2.y;
        float p3 = q2.x * k3.x + q2.y * k3.y;
        p0 += __shfl_xor(p0, 1); p1 += __shfl_xor(p1, 1); p2 += __shfl_xor(p2, 1); p3 += __shfl_xor(p3, 1);
        p0 += __shfl_xor(p0, 2); p1 += __shfl_xor(p1, 2); p2 += __shfl_xor(p2, 2); p3 += __shfl_xor(p3, 2);
        p0 += __shfl_xor(p0, 4); p1 += __shfl_xor(p1, 4); p2 += __shfl_xor(p2, 4); p3 += __shfl_xor(p3, 4);
        p0 += __shfl_xor(p0, 8); p1 += __shfl_xor(p1, 8); p2 += __shfl_xor(p2, 8); p3 += __shfl_xor(p3, 8);
        float e0v = expf(p0 * sc), e1v = expf(p1 * sc);
        float e2v = expf(p2 * sc), e3v = expf(p3 * sc);
        float2 v0 = up2(kv0.y), v1 = up2(kv1.y), v2 = up2(kv2.y), v3 = up2(kv3.y);
        accx += e0v * v0.x + e1v * v1.x + e2v * v2.x + e3v * v3.x;
        accy += e0v * v0.y + e1v * v1.y + e2v * v2.y + e3v * v3.y;
        dsum += (e0v + e1v) + (e2v + e3v);
    }
    for (; idx < e1; ++idx) {
        int s0 = srcs[idx];
        uint2 kv0 = *(const uint2*)&qkvs[(size_t)s0 * 512 + 128 + 4 * lane];
        float2 k0 = up2(kv0.x);
        float p0 = q2.x * k0.x + q2.y * k0.y;
        p0 += __shfl_xor(p0, 1);
        p0 += __shfl_xor(p0, 2);
        p0 += __shfl_xor(p0, 4);
        p0 += __shfl_xor(p0, 8);
        float e0v = expf(p0 * sc);
        float2 v0 = up2(kv0.y);
        accx += e0v * v0.x;
        accy += e0v * v0.y;
        dsum += e0v;
    }
    float dinv = 1.0f / (dsum + 1e-16f);
    float vx = accx * dinv + sk.x, vy = accy * dinv + sk.y;
    float sum = vx + vy;
    for (int msk = 1; msk < 64; msk <<= 1) sum += __shfl_xor(sum, msk);
    float mu = sum * (1.0f / 128.0f);
    float dx = vx - mu, dy = vy - mu;
    float sq = dx * dx + dy * dy;
    for (int msk = 1; msk < 64; msk <<= 1) sq += __shfl_xor(sq, msk);
    float rs = rsqrtf(sq * (1.0f / 128.0f) + 1e-5f);
    int c = 2 * lane;
    float o0 = dx * rs * gamma[c]     + beta[c];
    float o1 = dy * rs * gamma[c + 1] + beta[c + 1];
    o0 = fmaxf(o0, 0.f);
    o1 = fmaxf(o1, 0.f);
    *(unsigned*)&hout[(size_t)n * 128 + c] = pk2(o0, o1);
}

// ---------------------------------------------------------------- classifier (h is bf16)
__global__ __launch_bounds__(256) void out_gemm_kernel(
    const unsigned short* __restrict__ h, const float* __restrict__ Wout,
    const float* __restrict__ bout, float* __restrict__ out) {
    __shared__ float hs[32][132];
    __shared__ float ws[128 * NCLS_];
    __shared__ float bsd[NCLS_];
    int t = threadIdx.x;
    int n0 = blockIdx.x * 32;
    for (int i = t; i < 128 * NCLS_; i += 256) ws[i] = Wout[i];
    if (t < NCLS_) bsd[t] = bout[t];
    for (int i = t; i < 1024; i += 256) {
        int r = i >> 5, k4 = (i & 31) << 2;
        float4 a = make_float4(0.f, 0.f, 0.f, 0.f);
        if (n0 + r < N_NODES) {
            ushort4 u = *(const ushort4*)&h[(size_t)(n0 + r) * 128 + k4];
            a = make_float4(b2f(u.x), b2f(u.y), b2f(u.z), b2f(u.w));
        }
        *(float4*)&hs[r][k4] = a;
    }
    __syncthreads();
    int r = t >> 3, j0 = (t & 7) * 5;
    float acc[5];
    for (int j = 0; j < 5; ++j) acc[j] = bsd[j0 + j];
    for (int k = 0; k < 128; ++k) {
        float a = hs[r][k];
        for (int j = 0; j < 5; ++j) acc[j] += a * ws[k * NCLS_ + j0 + j];
    }
    int n = n0 + r;
    if (n < N_NODES) {
        for (int j = 0; j < 5; ++j) out[(size_t)n * NCLS_ + j0 + j] = acc[j];
    }
}

// ---------------------------------------------------------------- launch
extern "C" void kernel_launch(void* const* d_in, const int* in_sizes, int n_in,
                              void* d_out, int out_size, void* d_ws, size_t ws_size,
                              hipStream_t stream) {
    const float* x    = (const float*)d_in[0];
    const int*   ei   = (const int*)d_in[1];
    const int*   src  = ei;
    const int*   dst  = ei + N_EDGES;
    const float* Wq   = (const float*)d_in[2];
    const float* bq   = (const float*)d_in[3];
    const float* Wk   = (const float*)d_in[4];
    const float* bk   = (const float*)d_in[5];
    const float* Wv   = (const float*)d_in[6];
    const float* bv   = (const float*)d_in[7];
    const float* Wsk  = (const float*)d_in[8];
    const float* bsk  = (const float*)d_in[9];
    const float* gmm  = (const float*)d_in[10];
    const float* bta  = (const float*)d_in[11];
    const float* Wout = (const float*)d_in[12];
    const float* bout = (const float*)d_in[13];
    float* outp = (float*)d_out;

    char* p = (char*)d_ws;
    auto carve = [&](size_t bytes) {
        char* r = p;
        p += (bytes + 255) & ~(size_t)255;
        return r;
    };
    unsigned short* qkvs = (unsigned short*)carve((size_t)N_NODES * 512 * 2);
    unsigned short* h    = (unsigned short*)carve((size_t)N_NODES * 128 * 2);
    unsigned short* Wbf  = (unsigned short*)carve((size_t)131072 * 2);
    int* deg     = (int*)carve((size_t)N_NODES * 4);
    int* rowptr  = (int*)carve((size_t)(N_NODES + 1) * 4);
    int* cursor  = (int*)carve((size_t)N_NODES * 4);
    int* srcs    = (int*)carve((size_t)N_EDGES * 4);
    int* sums    = (int*)carve((size_t)NSCAN_BLOCKS * 4);

    // W -> bf16 fragment layout (once per launch)
    wconv_kernel<<<512, 256, 0, stream>>>(Wq, Wk, Wv, Wsk, Wbf);

    // CSR by dst (reused by both layers)
    zero_i32_kernel<<<(N_NODES + 255) / 256, 256, 0, stream>>>(deg, N_NODES);
    hist_kernel<<<2048, 256, 0, stream>>>(dst, deg);
    scan_block_kernel<<<NSCAN_BLOCKS, 1024, 0, stream>>>(deg, rowptr, sums);
    scan_sums_kernel<<<1, 128, 0, stream>>>(sums);
    scan_add_kernel<<<(N_NODES + 255) / 256, 256, 0, stream>>>(rowptr, sums, cursor);
    scatter_kernel<<<2048, 256, 0, stream>>>(src, dst, cursor, srcs);

    for (int l = 0; l < 2; ++l) {
        const void* hin = l ? (const void*)h : (const void*)x;
        gemm_qkvs_kernel<<<(N_NODES + 63) / 64, 256, 0, stream>>>(
            hin, l, Wbf + (size_t)l * 65536,
            bq + l * 128, bk + l * 128, bv + l * 128, bsk + l * 128, qkvs);
        edge_fused_kernel<<<(N_NODES + 3) / 4, 256, 0, stream>>>(
            qkvs, srcs, rowptr, gmm + l * 128, bta + l * 128, h);
    }
    out_gemm_kernel<<<(N_NODES + 31) / 32, 256, 0, stream>>>(h, Wout, bout, outp);
}

// Round 9
// 703.910 us; speedup vs baseline: 2.9373x; 1.0178x over previous
//
#include <hip/hip_runtime.h>
#include <math.h>

#define N_NODES 100000
#define N_EDGES 1600000
#define NCLS_ 40
#define NSCAN_BLOCKS ((N_NODES + 1023) / 1024)   // 98
#define DRANGE 12500                              // N_NODES / 8 XCD groups

typedef short bf16x8 __attribute__((ext_vector_type(8)));
typedef float f32x4 __attribute__((ext_vector_type(4)));

// bf16 helpers (RNE pack, exact unpack)
__device__ __forceinline__ unsigned short f2b(float f) {
    union { float f; unsigned u; } v; v.f = f;
    unsigned r = v.u + 0x7fffu + ((v.u >> 16) & 1u);
    return (unsigned short)(r >> 16);
}
__device__ __forceinline__ float2 up2(unsigned u) {   // packed pair -> floats
    union { unsigned u; float f; } a, b;
    a.u = u << 16; b.u = u & 0xffff0000u;
    return make_float2(a.f, b.f);
}
__device__ __forceinline__ unsigned pk2(float x, float y) {
    return (unsigned)f2b(x) | ((unsigned)f2b(y) << 16);
}
__device__ __forceinline__ float b2f(unsigned short s) {
    union { unsigned u; float f; } v; v.u = ((unsigned)s) << 16;
    return v.f;
}

// qkvs row layout (512 shorts):
//   [0,128)    Q, channel c at c
//   [128,384)  K/V interleaved 16B/lane: half-lane hl (0..31) owns shorts
//              128+8hl..128+8hl+7 = {K4hl..K4hl+3, V4hl..V4hl+3}
//   [384,512)  S (skip), channel c at 384+c

// ---------------------------------------------------------------- utils
__global__ void zero_i32_kernel(int* __restrict__ p, int n) {
    int i = blockIdx.x * blockDim.x + threadIdx.x;
    if (i < n) p[i] = 0;
}

// W preconvert: fp32 [L][128k][128col] -> bf16 B-fragment layout
// Wbf[l][mat][g][n][k], n=col within 64-group, k=0..127.  131072 shorts.
__global__ __launch_bounds__(256) void wconv_kernel(
    const float* __restrict__ Wq, const float* __restrict__ Wk,
    const float* __restrict__ Wv, const float* __restrict__ Ws,
    unsigned short* __restrict__ Wbf) {
    int tid = blockIdx.x * 256 + threadIdx.x;
    if (tid >= 131072) return;
    int k   = tid & 127;
    int n   = (tid >> 7) & 63;
    int g   = (tid >> 13) & 1;
    int mat = (tid >> 14) & 3;
    int l   = tid >> 16;
    const float* W = (mat == 0) ? Wq : (mat == 1) ? Wk : (mat == 2) ? Wv : Ws;
    Wbf[tid] = f2b(W[l * 16384 + k * 128 + g * 64 + n]);
}

// ---------------------------------------------------------------- CSR build
__global__ __launch_bounds__(256) void hist_kernel(
    const int* __restrict__ dst, int* __restrict__ deg) {
    int group = blockIdx.x & 7;
    int gblk  = blockIdx.x >> 3;
    int nblk  = gridDim.x >> 3;
    int lo = group * DRANGE, hi = lo + DRANGE;
    for (int i = gblk * 256 + threadIdx.x; i < N_EDGES; i += nblk * 256) {
        int d = dst[i];
        if (d >= lo && d < hi) atomicAdd(&deg[d], 1);
    }
}

__global__ __launch_bounds__(1024) void scan_block_kernel(
    const int* __restrict__ deg, int* __restrict__ rowptr, int* __restrict__ sums) {
    __shared__ int tmp[1024];
    int t = threadIdx.x;
    int i = blockIdx.x * 1024 + t;
    int v = (i < N_NODES) ? deg[i] : 0;
    tmp[t] = v;
    __syncthreads();
    for (int d = 1; d < 1024; d <<= 1) {
        int add = (t >= d) ? tmp[t - d] : 0;
        __syncthreads();
        tmp[t] += add;
        __syncthreads();
    }
    if (i < N_NODES) rowptr[i] = tmp[t] - v;
    if (t == 1023) sums[blockIdx.x] = tmp[1023];
}

__global__ __launch_bounds__(128) void scan_sums_kernel(int* __restrict__ sums) {
    __shared__ int tmp[128];
    int t = threadIdx.x;
    int v = (t < NSCAN_BLOCKS) ? sums[t] : 0;
    tmp[t] = v;
    __syncthreads();
    for (int d = 1; d < 128; d <<= 1) {
        int add = (t >= d) ? tmp[t - d] : 0;
        __syncthreads();
        tmp[t] += add;
        __syncthreads();
    }
    if (t < NSCAN_BLOCKS) sums[t] = tmp[t] - v;
}

__global__ void scan_add_kernel(int* __restrict__ rowptr, const int* __restrict__ sums,
                                int* __restrict__ cursor) {
    int i = blockIdx.x * blockDim.x + threadIdx.x;
    if (i < N_NODES) {
        int val = rowptr[i] + sums[i >> 10];
        rowptr[i] = val;
        cursor[i] = val;
    }
    if (i == 0) rowptr[N_NODES] = N_EDGES;
}

__global__ __launch_bounds__(256) void scatter_kernel(
    const int* __restrict__ src, const int* __restrict__ dst,
    int* __restrict__ cursor, int* __restrict__ srcs) {
    int group = blockIdx.x & 7;
    int gblk  = blockIdx.x >> 3;
    int nblk  = gridDim.x >> 3;
    int lo = group * DRANGE, hi = lo + DRANGE;
    for (int i = gblk * 256 + threadIdx.x; i < N_EDGES; i += nblk * 256) {
        int d = dst[i];
        if (d >= lo && d < hi) {
            int pos = atomicAdd(&cursor[d], 1);
            srcs[pos] = src[i];
        }
    }
}

// ---------------------------------------------------------------- QKVS GEMM (bf16 MFMA)
// One block per 64-row tile, all 512 cols; Bs double-buffered with register
// prefetch; W pre-converted to bf16 fragment layout (conflict-free staging).
__global__ __launch_bounds__(256) void gemm_qkvs_kernel(
    const void* __restrict__ Ap, int a_is_bf16,
    const unsigned short* __restrict__ Wbf,   // this layer: [mat][g][64][128]
    const float* __restrict__ b0, const float* __restrict__ b1,
    const float* __restrict__ b2, const float* __restrict__ b3,
    unsigned short* __restrict__ out) {
    __shared__ unsigned short As[64][138];
    __shared__ unsigned short Bs[2][64][138];
    int t = threadIdx.x;
    int row0 = blockIdx.x * 64;

    if (a_is_bf16) {
        const unsigned short* A = (const unsigned short*)Ap;
        for (int i = 0; i < 8; ++i) {
            int idx = t + i * 256;
            int r = idx >> 5, k4 = (idx & 31) << 2;
            ushort4 v = make_ushort4(0, 0, 0, 0);
            if (row0 + r < N_NODES) v = *(const ushort4*)&A[(size_t)(row0 + r) * 128 + k4];
            *(ushort4*)&As[r][k4] = v;
        }
    } else {
        const float* A = (const float*)Ap;
        for (int i = 0; i < 8; ++i) {
            int idx = t + i * 256;
            int r = idx >> 5, k4 = (idx & 31) << 2;
            float4 v = make_float4(0.f, 0.f, 0.f, 0.f);
            if (row0 + r < N_NODES) v = *(const float4*)&A[(size_t)(row0 + r) * 128 + k4];
            ushort4 o;
            o.x = f2b(v.x); o.y = f2b(v.y); o.z = f2b(v.z); o.w = f2b(v.w);
            *(ushort4*)&As[r][k4] = o;
        }
    }

    int wv = t >> 6, lane = t & 63;
    int ln = lane & 15, quad = lane >> 4;

    ushort4 pf[8];
    {
        const unsigned short* Wg = Wbf;
        for (int i = 0; i < 8; ++i) {
            int idx = t + i * 256;
            pf[i] = *(const ushort4*)&Wg[((idx >> 5) << 7) + ((idx & 31) << 2)];
        }
        for (int i = 0; i < 8; ++i) {
            int idx = t + i * 256;
            *(ushort4*)&Bs[0][idx >> 5][(idx & 31) << 2] = pf[i];
        }
    }
    __syncthreads();

    #pragma unroll
    for (int g = 0; g < 8; ++g) {
        int mat = g >> 1;
        int cur = g & 1;
        const float* bias = (mat == 0) ? b0 : (mat == 1) ? b1 : (mat == 2) ? b2 : b3;
        int cb = (g & 1) * 64;

        if (g < 7) {
            const unsigned short* Wg = Wbf + (size_t)(g + 1) * 8192;
            for (int i = 0; i < 8; ++i) {
                int idx = t + i * 256;
                pf[i] = *(const ushort4*)&Wg[((idx >> 5) << 7) + ((idx & 31) << 2)];
            }
        }

        f32x4 acc[4];
        for (int c = 0; c < 4; ++c) acc[c] = (f32x4){0.f, 0.f, 0.f, 0.f};
        for (int ks = 0; ks < 4; ++ks) {
            int k0 = ks * 32 + quad * 8;
            bf16x8 a = *(bf16x8*)&As[wv * 16 + ln][k0];
            for (int c = 0; c < 4; ++c) {
                bf16x8 b = *(bf16x8*)&Bs[cur][c * 16 + ln][k0];
                acc[c] = __builtin_amdgcn_mfma_f32_16x16x32_bf16(a, b, acc[c], 0, 0, 0);
            }
        }

        // epilogue through the 16B-interleave position map
        for (int c = 0; c < 4; ++c) {
            int colInMat = cb + c * 16 + ln;
            float bb = bias[colInMat];
            int pos;
            if (mat == 0)      pos = colInMat;
            else if (mat == 3) pos = 384 + colInMat;
            else               pos = 128 + ((colInMat >> 2) << 3) + ((mat == 2) ? 4 : 0) + (colInMat & 3);
            for (int r = 0; r < 4; ++r) {
                int row = row0 + wv * 16 + quad * 4 + r;
                if (row < N_NODES)
                    out[(size_t)row * 512 + pos] = f2b(acc[c][r] + bb);
            }
        }

        if (g < 7) {
            int nxt = cur ^ 1;
            for (int i = 0; i < 8; ++i) {
                int idx = t + i * 256;
                *(ushort4*)&Bs[nxt][idx >> 5][(idx & 31) << 2] = pf[i];
            }
        }
        __syncthreads();
    }
}

// ---------------------------------------------------------------- fused edge pass
// HALF-WAVE per edge: 32 lanes x 16 B cover one edge's full KV row, so each
// wave processes 2 edges/iteration (R8: VALUBusy 94% at 1 edge/wave-iter —
// VALU-issue-bound).  Head reduction = 3 shfl rounds (8 lanes/head); halves
// combined once at the end via shfl_xor(32); LN uses duplicated-half sums
// (/256).  __expf = native v_exp_f32 (OCML expf was ~15 VALU/edge).
__global__ __launch_bounds__(256) void edge_fused_kernel(
    const unsigned short* __restrict__ qkvs,
    const int* __restrict__ srcs, const int* __restrict__ rowptr,
    const float* __restrict__ gamma, const float* __restrict__ beta,
    unsigned short* __restrict__ hout) {
    int n = (blockIdx.x * 256 + threadIdx.x) >> 6;
    int lane = threadIdx.x & 63;
    if (n >= N_NODES) return;
    int half = lane >> 5, hl = lane & 31;
    const unsigned short* qrow = qkvs + (size_t)n * 512;
    uint2 qu = *(const uint2*)&qrow[4 * hl];
    float2 q01 = up2(qu.x), q23 = up2(qu.y);
    uint2 su = *(const uint2*)&qrow[384 + 4 * hl];
    float2 sk01 = up2(su.x), sk23 = up2(su.y);
    int e0 = rowptr[n], e1 = rowptr[n + 1];
    float a0 = 0.f, a1 = 0.f, a2 = 0.f, a3 = 0.f, dsum = 0.f;
    const float sc = 0.17677669529663687f;   // 1/sqrt(32)
    int idx = e0;
    for (; idx + 3 < e1; idx += 4) {
        int sA = srcs[idx + half];
        int sB = srcs[idx + 2 + half];
        uint4 kvA = *(const uint4*)&qkvs[(size_t)sA * 512 + 128 + 8 * hl];
        uint4 kvB = *(const uint4*)&qkvs[(size_t)sB * 512 + 128 + 8 * hl];
        float2 kA01 = up2(kvA.x), kA23 = up2(kvA.y);
        float2 kB01 = up2(kvB.x), kB23 = up2(kvB.y);
        float pA = q01.x * kA01.x + q01.y * kA01.y + q23.x * kA23.x + q23.y * kA23.y;
        float pB = q01.x * kB01.x + q01.y * kB01.y + q23.x * kB23.x + q23.y * kB23.y;
        pA += __shfl_xor(pA, 1); pB += __shfl_xor(pB, 1);
        pA += __shfl_xor(pA, 2); pB += __shfl_xor(pB, 2);
        pA += __shfl_xor(pA, 4); pB += __shfl_xor(pB, 4);
        float eA = __expf(pA * sc), eB = __expf(pB * sc);
        float2 vA01 = up2(kvA.z), vA23 = up2(kvA.w);
        float2 vB01 = up2(kvB.z), vB23 = up2(kvB.w);
        a0 += eA * vA01.x + eB * vB01.x;
        a1 += eA * vA01.y + eB * vB01.y;
        a2 += eA * vA23.x + eB * vB23.x;
        a3 += eA * vA23.y + eB * vB23.y;
        dsum += eA + eB;
    }
    for (; idx < e1; idx += 2) {
        int i = idx + half;
        bool valid = i < e1;
        int sA = srcs[valid ? i : e1 - 1];
        uint4 kvA = *(const uint4*)&qkvs[(size_t)sA * 512 + 128 + 8 * hl];
        float2 kA01 = up2(kvA.x), kA23 = up2(kvA.y);
        float pA = q01.x * kA01.x + q01.y * kA01.y + q23.x * kA23.x + q23.y * kA23.y;
        pA += __shfl_xor(pA, 1);
        pA += __shfl_xor(pA, 2);
        pA += __shfl_xor(pA, 4);
        float eA = valid ? __expf(pA * sc) : 0.f;
        float2 vA01 = up2(kvA.z), vA23 = up2(kvA.w);
        a0 += eA * vA01.x; a1 += eA * vA01.y;
        a2 += eA * vA23.x; a3 += eA * vA23.y;
        dsum += eA;
    }
    // combine halves (lanes l and l+32 hold same channels, different edges)
    a0 += __shfl_xor(a0, 32); a1 += __shfl_xor(a1, 32);
    a2 += __shfl_xor(a2, 32); a3 += __shfl_xor(a3, 32);
    dsum += __shfl_xor(dsum, 32);
    float dinv = 1.0f / (dsum + 1e-16f);
    float o0 = a0 * dinv + sk01.x, o1 = a1 * dinv + sk01.y;
    float o2 = a2 * dinv + sk23.x, o3 = a3 * dinv + sk23.y;
    float sum = o0 + o1 + o2 + o3;
    for (int m = 1; m < 64; m <<= 1) sum += __shfl_xor(sum, m);
    float mu = sum * (1.0f / 256.0f);          // halves duplicated -> /256
    float d0 = o0 - mu, d1 = o1 - mu, d2 = o2 - mu, d3 = o3 - mu;
    float sq = d0 * d0 + d1 * d1 + d2 * d2 + d3 * d3;
    for (int m = 1; m < 64; m <<= 1) sq += __shfl_xor(sq, m);
    float rs = rsqrtf(sq * (1.0f / 256.0f) + 1e-5f);
    if (half == 0) {
        float4 g4 = *(const float4*)&gamma[4 * hl];
        float4 b4 = *(const float4*)&beta[4 * hl];
        float r0 = fmaxf(d0 * rs * g4.x + b4.x, 0.f);
        float r1 = fmaxf(d1 * rs * g4.y + b4.y, 0.f);
        float r2 = fmaxf(d2 * rs * g4.z + b4.z, 0.f);
        float r3 = fmaxf(d3 * rs * g4.w + b4.w, 0.f);
        uint2 w;
        w.x = pk2(r0, r1);
        w.y = pk2(r2, r3);
        *(uint2*)&hout[(size_t)n * 128 + 4 * hl] = w;
    }
}

// ---------------------------------------------------------------- classifier (h is bf16)
__global__ __launch_bounds__(256) void out_gemm_kernel(
    const unsigned short* __restrict__ h, const float* __restrict__ Wout,
    const float* __restrict__ bout, float* __restrict__ out) {
    __shared__ float hs[32][132];
    __shared__ float ws[128 * NCLS_];
    __shared__ float bsd[NCLS_];
    int t = threadIdx.x;
    int n0 = blockIdx.x * 32;
    for (int i = t; i < 128 * NCLS_; i += 256) ws[i] = Wout[i];
    if (t < NCLS_) bsd[t] = bout[t];
    for (int i = t; i < 1024; i += 256) {
        int r = i >> 5, k4 = (i & 31) << 2;
        float4 a = make_float4(0.f, 0.f, 0.f, 0.f);
        if (n0 + r < N_NODES) {
            ushort4 u = *(const ushort4*)&h[(size_t)(n0 + r) * 128 + k4];
            a = make_float4(b2f(u.x), b2f(u.y), b2f(u.z), b2f(u.w));
        }
        *(float4*)&hs[r][k4] = a;
    }
    __syncthreads();
    int r = t >> 3, j0 = (t & 7) * 5;
    float acc[5];
    for (int j = 0; j < 5; ++j) acc[j] = bsd[j0 + j];
    for (int k = 0; k < 128; ++k) {
        float a = hs[r][k];
        for (int j = 0; j < 5; ++j) acc[j] += a * ws[k * NCLS_ + j0 + j];
    }
    int n = n0 + r;
    if (n < N_NODES) {
        for (int j = 0; j < 5; ++j) out[(size_t)n * NCLS_ + j0 + j] = acc[j];
    }
}

// ---------------------------------------------------------------- launch
extern "C" void kernel_launch(void* const* d_in, const int* in_sizes, int n_in,
                              void* d_out, int out_size, void* d_ws, size_t ws_size,
                              hipStream_t stream) {
    const float* x    = (const float*)d_in[0];
    const int*   ei   = (const int*)d_in[1];
    const int*   src  = ei;
    const int*   dst  = ei + N_EDGES;
    const float* Wq   = (const float*)d_in[2];
    const float* bq   = (const float*)d_in[3];
    const float* Wk   = (const float*)d_in[4];
    const float* bk   = (const float*)d_in[5];
    const float* Wv   = (const float*)d_in[6];
    const float* bv   = (const float*)d_in[7];
    const float* Wsk  = (const float*)d_in[8];
    const float* bsk  = (const float*)d_in[9];
    const float* gmm  = (const float*)d_in[10];
    const float* bta  = (const float*)d_in[11];
    const float* Wout = (const float*)d_in[12];
    const float* bout = (const float*)d_in[13];
    float* outp = (float*)d_out;

    char* p = (char*)d_ws;
    auto carve = [&](size_t bytes) {
        char* r = p;
        p += (bytes + 255) & ~(size_t)255;
        return r;
    };
    unsigned short* qkvs = (unsigned short*)carve((size_t)N_NODES * 512 * 2);
    unsigned short* h    = (unsigned short*)carve((size_t)N_NODES * 128 * 2);
    unsigned short* Wbf  = (unsigned short*)carve((size_t)131072 * 2);
    int* deg     = (int*)carve((size_t)N_NODES * 4);
    int* rowptr  = (int*)carve((size_t)(N_NODES + 1) * 4);
    int* cursor  = (int*)carve((size_t)N_NODES * 4);
    int* srcs    = (int*)carve((size_t)N_EDGES * 4);
    int* sums    = (int*)carve((size_t)NSCAN_BLOCKS * 4);

    wconv_kernel<<<512, 256, 0, stream>>>(Wq, Wk, Wv, Wsk, Wbf);

    zero_i32_kernel<<<(N_NODES + 255) / 256, 256, 0, stream>>>(deg, N_NODES);
    hist_kernel<<<2048, 256, 0, stream>>>(dst, deg);
    scan_block_kernel<<<NSCAN_BLOCKS, 1024, 0, stream>>>(deg, rowptr, sums);
    scan_sums_kernel<<<1, 128, 0, stream>>>(sums);
    scan_add_kernel<<<(N_NODES + 255) / 256, 256, 0, stream>>>(rowptr, sums, cursor);
    scatter_kernel<<<2048, 256, 0, stream>>>(src, dst, cursor, srcs);

    for (int l = 0; l < 2; ++l) {
        const void* hin = l ? (const void*)h : (const void*)x;
        gemm_qkvs_kernel<<<(N_NODES + 63) / 64, 256, 0, stream>>>(
            hin, l, Wbf + (size_t)l * 65536,
            bq + l * 128, bk + l * 128, bv + l * 128, bsk + l * 128, qkvs);
        edge_fused_kernel<<<(N_NODES + 3) / 4, 256, 0, stream>>>(
            qkvs, srcs, rowptr, gmm + l * 128, bta + l * 128, h);
    }
    out_gemm_kernel<<<(N_NODES + 31) / 32, 256, 0, stream>>>(h, Wout, bout, outp);
}